// Round 1
// baseline (395.193 us; speedup 1.0000x reference)
//
#include <hip/hip_runtime.h>
#include <cstdint>

constexpr int kDM = 2048;   // d_model
constexpr int kNH = 16;     // heads
constexpr int kDH = 128;    // head dim
constexpr int kS  = 2048;   // seq
constexpr int kM  = 4096;   // B*S rows

typedef __bf16 bf16x8 __attribute__((ext_vector_type(8)));
typedef float  f32x4  __attribute__((ext_vector_type(4)));

__device__ __forceinline__ unsigned short f2bf(float f) {
    union { float f; unsigned u; } v; v.f = f;
    unsigned u = v.u;
    u += 0x7fffu + ((u >> 16) & 1u);   // RNE
    return (unsigned short)(u >> 16);
}
__device__ __forceinline__ float bf2f(unsigned short b) {
    union { unsigned u; float f; } v; v.u = ((unsigned)b) << 16;
    return v.f;
}
__device__ __forceinline__ float fast_exp2(float x) {
#if __has_builtin(__builtin_amdgcn_exp2f)
    return __builtin_amdgcn_exp2f(x);
#else
    return exp2f(x);
#endif
}
// async global->LDS, 16B per lane, LDS dest = wave-uniform base + lane*16
__device__ __forceinline__ void load_lds16(const void* g, void* l) {
    auto gp = (__attribute__((address_space(1))) unsigned int*)(uintptr_t)g;
    auto lp = (__attribute__((address_space(3))) unsigned int*)(uintptr_t)l;
    __builtin_amdgcn_global_load_lds(gp, lp, 16, 0, 0);
}

// ---------------- LayerNorm: fp32 in -> bf16 out ----------------
__global__ __launch_bounds__(256) void ln_kernel(const float* __restrict__ X,
        const float* __restrict__ g, const float* __restrict__ b,
        unsigned short* __restrict__ Xn) {
    const int row = blockIdx.x;
    const float* xr = X + (size_t)row * kDM;
    const float4 v0 = ((const float4*)xr)[threadIdx.x];
    const float4 v1 = ((const float4*)xr)[threadIdx.x + 256];
    float s  = v0.x + v0.y + v0.z + v0.w + v1.x + v1.y + v1.z + v1.w;
    float sq = v0.x*v0.x + v0.y*v0.y + v0.z*v0.z + v0.w*v0.w
             + v1.x*v1.x + v1.y*v1.y + v1.z*v1.z + v1.w*v1.w;
    #pragma unroll
    for (int m = 1; m < 64; m <<= 1) { s += __shfl_xor(s, m); sq += __shfl_xor(sq, m); }
    __shared__ float ls[4], lq[4];
    if ((threadIdx.x & 63) == 0) { ls[threadIdx.x >> 6] = s; lq[threadIdx.x >> 6] = sq; }
    __syncthreads();
    s  = ls[0] + ls[1] + ls[2] + ls[3];
    sq = lq[0] + lq[1] + lq[2] + lq[3];
    const float mu   = s * (1.0f / kDM);
    const float rstd = rsqrtf(sq * (1.0f / kDM) - mu * mu + 1e-5f);
    unsigned short* xo = Xn + (size_t)row * kDM;
    {
        const float4 gg = ((const float4*)g)[threadIdx.x];
        const float4 bb = ((const float4*)b)[threadIdx.x];
        ushort4 o;
        o.x = f2bf((v0.x - mu) * rstd * gg.x + bb.x);
        o.y = f2bf((v0.y - mu) * rstd * gg.y + bb.y);
        o.z = f2bf((v0.z - mu) * rstd * gg.z + bb.z);
        o.w = f2bf((v0.w - mu) * rstd * gg.w + bb.w);
        ((ushort4*)xo)[threadIdx.x] = o;
    }
    {
        const float4 gg = ((const float4*)g)[threadIdx.x + 256];
        const float4 bb = ((const float4*)b)[threadIdx.x + 256];
        ushort4 o;
        o.x = f2bf((v1.x - mu) * rstd * gg.x + bb.x);
        o.y = f2bf((v1.y - mu) * rstd * gg.y + bb.y);
        o.z = f2bf((v1.z - mu) * rstd * gg.z + bb.z);
        o.w = f2bf((v1.w - mu) * rstd * gg.w + bb.w);
        ((ushort4*)xo)[threadIdx.x + 256] = o;
    }
}

// ------------- weight transpose+cast: W[K][N] f32 -> Wt[N][K] bf16 -------------
__global__ __launch_bounds__(256) void wt_kernel(
        const float* __restrict__ W0, const float* __restrict__ W1,
        const float* __restrict__ W2, const float* __restrict__ W3,
        unsigned short* __restrict__ T0, unsigned short* __restrict__ T1,
        unsigned short* __restrict__ T2, unsigned short* __restrict__ T3) {
    const float* W; unsigned short* T;
    switch (blockIdx.z) {
        case 0:  W = W0; T = T0; break;
        case 1:  W = W1; T = T1; break;
        case 2:  W = W2; T = T2; break;
        default: W = W3; T = T3; break;
    }
    __shared__ float tile[32][33];
    const int tx = threadIdx.x & 31, ty = threadIdx.x >> 5;
    const int r0 = blockIdx.y * 32, c0 = blockIdx.x * 32;
    #pragma unroll
    for (int i = 0; i < 4; ++i)
        tile[ty + i * 8][tx] = W[(size_t)(r0 + ty + i * 8) * kDM + c0 + tx];
    __syncthreads();
    #pragma unroll
    for (int i = 0; i < 4; ++i)
        T[(size_t)(c0 + ty + i * 8) * kDM + r0 + tx] = f2bf(tile[tx][ty + i * 8]);
}

// --- bias concat: [bq|bk|bv] -> 6144 floats ---
__global__ __launch_bounds__(256) void bias_pack(const float* __restrict__ bq,
        const float* __restrict__ bk, const float* __restrict__ bv,
        float* __restrict__ o) {
    const int i = blockIdx.x * 256 + threadIdx.x;
    o[i] = (i < 2048) ? bq[i] : ((i < 4096) ? bk[i - 2048] : bv[i - 4096]);
}

// --- V transpose: [bh][s][dh] bf16 -> [bh][dh][s] bf16, 64x64 tiles ---
__global__ __launch_bounds__(256) void vtr_kernel(const unsigned short* __restrict__ Vin,
                                                  unsigned short* __restrict__ Vout) {
    __shared__ __align__(16) unsigned short tile[64 * 72];
    const int bhz = blockIdx.z;
    const int s0 = blockIdx.x * 64, d0 = blockIdx.y * 64;
    const int t = threadIdx.x;
    const unsigned short* src = Vin + ((size_t)bhz * kS + s0) * kDH + d0;
    #pragma unroll
    for (int i = 0; i < 2; ++i) {
        const int r = (t >> 3) + 32 * i;
        const int g = t & 7;
        *(uint4*)(tile + r * 72 + g * 8) = *(const uint4*)(src + (size_t)r * kDH + g * 8);
    }
    __syncthreads();
    unsigned short* dst = Vout + ((size_t)bhz * kDH + d0) * kS + s0;
    #pragma unroll
    for (int i = 0; i < 2; ++i) {
        const int d = (t >> 3) + 32 * i;
        const int sg = t & 7;
        union { unsigned short u[8]; uint4 v; } o;
        #pragma unroll
        for (int j = 0; j < 8; ++j)
            o.u[j] = tile[(sg * 8 + j) * 72 + d];
        *(uint4*)(dst + (size_t)d * kS + sg * 8) = o.v;
    }
}

// ------------- GEMM: C = A[M,K]bf16 @ Bt[N,K]^T bf16 + bias -------------
// BK=64 via two 32-k sub-buffers (half the barrier count vs BK=32); staging is
// ascending-contiguous per lane group (no source swizzle -- R4 showed that
// breaks VMEM coalescing and costs more than the LDS conflicts it removes).
// Grid: blockIdx.x = m-tile (fastest; B-column stays L2-hot), blockIdx.y = n-tile.
// fp32out=1: fp32 row-major to C0 (N<=2048).
// fp32out=0: bf16 [B,H,S,Dh] out; proj = n0>>11 selects C0/C1/C2; scale0 on proj 0.
__global__ __launch_bounds__(256) void gemm_kernel(
        const unsigned short* __restrict__ A, const unsigned short* __restrict__ Bt,
        const float* __restrict__ bias, void* __restrict__ C0, void* __restrict__ C1,
        void* __restrict__ C2, const float scale0, const int fp32out) {
    __shared__ __align__(16) unsigned short ldsA[2][128 * 32];
    __shared__ __align__(16) unsigned short ldsB[2][128 * 32];
    const int m0 = blockIdx.x * 128, n0 = blockIdx.y * 128;
    const int tid = threadIdx.x, lane = tid & 63, w = tid >> 6;
    const int wm = (w >> 1) * 64, wn = (w & 1) * 64;
    const int quad = lane >> 4, l15 = lane & 15;
    f32x4 acc[4][4] = {};
    const int srow = lane >> 2, scol = (lane & 3) * 8;
    for (int k0 = 0; k0 < kDM; k0 += 64) {
        __syncthreads();
        #pragma unroll
        for (int sub = 0; sub < 2; ++sub) {
            #pragma unroll
            for (int i = 0; i < 2; ++i) {
                const int c = w + i * 4;
                const int row = c * 16 + srow;
                const int kc = k0 + sub * 32 + scol;
                load_lds16(A  + (size_t)(m0 + row) * kDM + kc, &ldsA[sub][c * 512]);
                load_lds16(Bt + (size_t)(n0 + row) * kDM + kc, &ldsB[sub][c * 512]);
            }
        }
        __syncthreads();
        #pragma unroll
        for (int sub = 0; sub < 2; ++sub) {
            bf16x8 af[4], bfr[4];
            #pragma unroll
            for (int mt = 0; mt < 4; ++mt)
                af[mt] = *(const bf16x8*)(&ldsA[sub][(wm + mt * 16 + l15) * 32 + quad * 8]);
            #pragma unroll
            for (int nt = 0; nt < 4; ++nt)
                bfr[nt] = *(const bf16x8*)(&ldsB[sub][(wn + nt * 16 + l15) * 32 + quad * 8]);
            #pragma unroll
            for (int mt = 0; mt < 4; ++mt)
                #pragma unroll
                for (int nt = 0; nt < 4; ++nt)
                    acc[mt][nt] = __builtin_amdgcn_mfma_f32_16x16x32_bf16(af[mt], bfr[nt], acc[mt][nt], 0, 0, 0);
        }
    }
    const int proj = n0 >> 11;
    void* Cb = (proj == 0) ? C0 : ((proj == 1) ? C1 : C2);
    const float scl = (proj == 0) ? scale0 : 1.0f;
    #pragma unroll
    for (int mt = 0; mt < 4; ++mt) {
        #pragma unroll
        for (int nt = 0; nt < 4; ++nt) {
            const int ng = n0 + wn + nt * 16 + l15;
            const float bv = bias[ng];
            const int col = ng & 2047;
            const int h = col >> 7, dh = col & 127;
            #pragma unroll
            for (int r = 0; r < 4; ++r) {
                const int mg = m0 + wm + mt * 16 + quad * 4 + r;
                const float val = (acc[mt][nt][r] + bv) * scl;
                if (fp32out) {
                    ((float*)Cb)[(size_t)mg * kDM + ng] = val;
                } else {
                    const int bb = mg >> 11, ss = mg & 2047;
                    ((unsigned short*)Cb)[((size_t)(bb * kNH + h) * kS + ss) * kDH + dh] = f2bf(val);
                }
            }
        }
    }
}

// ------------- causal flash attention, S^T form, paired q-tiles -------------
// Q,K: [B,H,S,Dh] bf16 (Q pre-scaled by log2e/sqrt(Dh)); Vt: [B,H,Dh,S] bf16;
// AV out: [M, DM] bf16.  Block handles q-tiles pr and 31-pr (uniform 33 key-iters).
// R(this): K/V LDS double-buffered (2-phase schedule, guide T3-minimum): stage
// tile kt+1 BEFORE computing tile kt; single vmcnt(0)+barrier per tile (the
// __syncthreads() drain now only waits on NEXT-tile loads, which had the whole
// QK^T+softmax+PV phase to land). LDS 40->72KB, still 2 blocks/CU.
__global__ __launch_bounds__(256, 2) void attn_kernel(
        const unsigned short* __restrict__ Q, const unsigned short* __restrict__ Kk,
        const unsigned short* __restrict__ Vt, unsigned short* __restrict__ AV) {
    __shared__ __align__(16) unsigned short ldsK[2][64 * 128];   // swizzled [key][d]
    __shared__ __align__(16) unsigned short ldsV[2][128 * 64];   // swizzled [d][key]
    __shared__ __align__(16) unsigned short ldsP[4 * 16 * 64];   // per-wave swizzled [q][key]
    const int bh = blockIdx.x, pr = blockIdx.y;
    const unsigned short* Qb = Q  + (size_t)bh * kS * kDH;
    const unsigned short* Kb = Kk + (size_t)bh * kS * kDH;
    const unsigned short* Vb = Vt + (size_t)bh * kDH * kS;
    const int tid = threadIdx.x, lane = tid & 63, w = tid >> 6;
    const int quad = lane >> 4, l15 = lane & 15;
    // staging offsets (source-swizzled so LDS layout is XOR-permuted)
    int kSrc[4], vSrc[4], ldst[4];
    #pragma unroll
    for (int i = 0; i < 4; ++i) {
        const int c = w * 4 + i;
        const int rK = c * 4 + (lane >> 4);
        const int gK = (lane & 15) ^ (rK & 15);
        kSrc[i] = rK * kDH + gK * 8;
        const int dV = c * 8 + (lane >> 3);
        const int gV = (lane & 7) ^ (dV & 7);
        vSrc[i] = dV * kS + gV * 8;
        ldst[i] = c * 512;
    }
    unsigned short* pw = ldsP + w * 1024;
    const int pswz = 2 * (l15 & 7);           // even XOR keeps 16B pairs intact
    const int bb = bh >> 4, h = bh & 15;
    for (int half = 0; half < 2; ++half) {
        const int qt = half ? (31 - pr) : pr;
        const int qrow0 = qt * 64 + w * 16;   // wave owns 16 q-rows
        bf16x8 qf[4];
        #pragma unroll
        for (int kk = 0; kk < 4; ++kk)
            qf[kk] = *(const bf16x8*)(Qb + (size_t)(qrow0 + l15) * kDH + kk * 32 + quad * 8);
        f32x4 accO[8] = {};
        float mrun = -3.0e38f, lrun = 0.0f;   // per-lane state for q = qrow0 + l15
        // prologue: stage tile 0 into buffer 0 (all waves already past the
        // previous half's tail barrier, so buf0 is free)
        #pragma unroll
        for (int i = 0; i < 4; ++i) {
            load_lds16(Kb + kSrc[i], &ldsK[0][ldst[i]]);
            load_lds16(Vb + vSrc[i], &ldsV[0][ldst[i]]);
        }
        __syncthreads();                      // vmcnt(0): tile 0 resident
        int cur = 0;
        for (int kt = 0; kt <= qt; ++kt) {
            if (kt < qt) {                    // issue next-tile loads; they fly
                #pragma unroll                // under this tile's compute
                for (int i = 0; i < 4; ++i) {
                    load_lds16(Kb + (size_t)(kt + 1) * (64 * kDH) + kSrc[i], &ldsK[cur ^ 1][ldst[i]]);
                    load_lds16(Vb + (kt + 1) * 64 + vSrc[i], &ldsV[cur ^ 1][ldst[i]]);
                }
            }
            // S^T = K . Q^T : A = K-frag (m=key), B = Q-frag (n=q)
            f32x4 accS[4] = {};
            #pragma unroll
            for (int kk = 0; kk < 4; ++kk) {
                bf16x8 kf[4];
                #pragma unroll
                for (int mt = 0; mt < 4; ++mt)
                    kf[mt] = *(const bf16x8*)(&ldsK[cur][(mt * 16 + l15) * 128 + (((kk * 4 + quad) ^ l15) << 3)]);
                #pragma unroll
                for (int mt = 0; mt < 4; ++mt)
                    accS[mt] = __builtin_amdgcn_mfma_f32_16x16x32_bf16(kf[mt], qf[kk], accS[mt], 0, 0, 0);
            }
            if (kt == qt) {                   // diagonal: mask key_local > q_local
                const int ql = w * 16 + l15;
                #pragma unroll
                for (int mt = 0; mt < 4; ++mt)
                    #pragma unroll
                    for (int r = 0; r < 4; ++r)
                        if (mt * 16 + quad * 4 + r > ql) accS[mt][r] = -3.0e38f;
            }
            // per-lane softmax over 16 in-register keys + 2 cross-quad shuffles
            float mx = accS[0][0];
            #pragma unroll
            for (int mt = 0; mt < 4; ++mt)
                #pragma unroll
                for (int r = 0; r < 4; ++r) mx = fmaxf(mx, accS[mt][r]);
            mx = fmaxf(mx, __shfl_xor(mx, 16));
            mx = fmaxf(mx, __shfl_xor(mx, 32));
            const float mnew = fmaxf(mrun, mx);
            const float al = fast_exp2(mrun - mnew);
            float rs = 0.f;
            #pragma unroll
            for (int mt = 0; mt < 4; ++mt) {
                ushort4 pk;
                unsigned short* pe = (unsigned short*)&pk;
                #pragma unroll
                for (int r = 0; r < 4; ++r) {
                    const float p = fast_exp2(accS[mt][r] - mnew);
                    const unsigned short pb = f2bf(p);
                    pe[r] = pb;
                    rs += bf2f(pb);           // keep l consistent with bf16 P
                }
                *(ushort4*)(pw + l15 * 64 + (((mt * 4 + quad) ^ pswz) << 2)) = pk;
            }
            rs += __shfl_xor(rs, 16);
            rs += __shfl_xor(rs, 32);
            lrun = lrun * al + rs;
            mrun = mnew;
            // broadcast alpha from state-lane (l15 == quad*4+r) to accO rows
            float albr[4];
            #pragma unroll
            for (int r = 0; r < 4; ++r)
                albr[r] = __shfl(al, (lane & 48) | (quad << 2) | r);
            #pragma unroll
            for (int dt = 0; dt < 8; ++dt)
                #pragma unroll
                for (int r = 0; r < 4; ++r)
                    accO[dt][r] *= albr[r];
            asm volatile("s_waitcnt lgkmcnt(0)" ::: "memory");  // P writes visible to own wave
            // O += P . V : A = P-frag (m=q), B = V-frag (n=d)
            #pragma unroll
            for (int kk = 0; kk < 2; ++kk) {
                const bf16x8 pa = *(const bf16x8*)(pw + l15 * 64 + (((kk * 8 + quad * 2) ^ pswz) << 2));
                #pragma unroll
                for (int dt = 0; dt < 8; ++dt) {
                    const bf16x8 vf = *(const bf16x8*)(&ldsV[cur][(dt * 16 + l15) * 64 + (((kk * 4 + quad) ^ (l15 & 7)) << 3)]);
                    accO[dt] = __builtin_amdgcn_mfma_f32_16x16x32_bf16(pa, vf, accO[dt], 0, 0, 0);
                }
            }
            // single barrier per tile: drains (only) the next-tile loads issued
            // above, which overlapped with this tile's compute
            __syncthreads();
            cur ^= 1;
        }
        float linv[4];
        #pragma unroll
        for (int r = 0; r < 4; ++r)
            linv[r] = __shfl(lrun, (lane & 48) | (quad << 2) | r);
        #pragma unroll
        for (int r = 0; r < 4; ++r) {
            const float inv = 1.0f / linv[r];
            unsigned short* orow = AV + ((size_t)bb * kS + qrow0 + quad * 4 + r) * kDM + h * kDH;
            #pragma unroll
            for (int dt = 0; dt < 8; ++dt)
                orow[dt * 16 + l15] = f2bf(accO[dt][r] * inv);
        }
    }
}

extern "C" void kernel_launch(void* const* d_in, const int* in_sizes, int n_in,
                              void* d_out, int out_size, void* d_ws, size_t ws_size,
                              hipStream_t stream) {
    const float* X   = (const float*)d_in[0];
    const float* lng = (const float*)d_in[1];
    const float* lnb = (const float*)d_in[2];
    const float* Wq  = (const float*)d_in[3];
    const float* bq  = (const float*)d_in[4];
    const float* Wk  = (const float*)d_in[5];
    const float* bk  = (const float*)d_in[6];
    const float* Wv  = (const float*)d_in[7];
    const float* bv  = (const float*)d_in[8];
    const float* Wo  = (const float*)d_in[9];
    const float* bo  = (const float*)d_in[10];
    float* out = (float*)d_out;

    char* p = (char*)d_ws;
    unsigned short* Xn  = (unsigned short*)p; p += (size_t)kM * kDM * 2;
    unsigned short* Wqt = (unsigned short*)p; p += (size_t)kDM * kDM * 2;  // Wq|Wk|Wv contiguous
    unsigned short* Wkt = (unsigned short*)p; p += (size_t)kDM * kDM * 2;
    unsigned short* Wvt = (unsigned short*)p; p += (size_t)kDM * kDM * 2;
    unsigned short* Wot = (unsigned short*)p; p += (size_t)kDM * kDM * 2;
    unsigned short* Qb  = (unsigned short*)p; p += (size_t)kM * kDM * 2;
    unsigned short* Kb  = (unsigned short*)p; p += (size_t)kM * kDM * 2;
    unsigned short* Vtb = (unsigned short*)p; p += (size_t)kM * kDM * 2;
    unsigned short* AV  = (unsigned short*)p; p += (size_t)kM * kDM * 2;
    unsigned short* Vtmp = AV;        // alias: consumed by vtr before attn writes AV
    float* biasc = (float*)Vtb;       // alias: consumed by qkv-gemm before vtr writes Vtb

    // log2(e)/sqrt(Dh): exp2-domain softmax
    const float qscale = 0.08838834764831845f * 1.4426950408889634f;

    ln_kernel<<<dim3(kM), dim3(256), 0, stream>>>(X, lng, lnb, Xn);
    wt_kernel<<<dim3(64, 64, 4), dim3(256), 0, stream>>>(Wq, Wk, Wv, Wo, Wqt, Wkt, Wvt, Wot);
    bias_pack<<<dim3(24), dim3(256), 0, stream>>>(bq, bk, bv, biasc);
    // fused QKV GEMM: N = 6144 over concatenated [Wqt|Wkt|Wvt]; m-tile fastest
    gemm_kernel<<<dim3(32, 48), dim3(256), 0, stream>>>(Xn, Wqt, biasc, Qb, Kb, Vtmp, qscale, 0);
    vtr_kernel<<<dim3(32, 2, 32), dim3(256), 0, stream>>>(Vtmp, Vtb);
    attn_kernel<<<dim3(32, 16), dim3(256), 0, stream>>>(Qb, Kb, Vtb, AV);
    gemm_kernel<<<dim3(32, 16), dim3(256), 0, stream>>>(AV, Wot, bo, out, out, out, 1.0f, 1);
}

// Round 2
// 387.997 us; speedup vs baseline: 1.0185x; 1.0185x over previous
//
#include <hip/hip_runtime.h>
#include <cstdint>

constexpr int kDM = 2048;   // d_model
constexpr int kNH = 16;     // heads
constexpr int kDH = 128;    // head dim
constexpr int kS  = 2048;   // seq
constexpr int kM  = 4096;   // B*S rows

typedef __bf16 bf16x8 __attribute__((ext_vector_type(8)));
typedef float  f32x4  __attribute__((ext_vector_type(4)));

__device__ __forceinline__ unsigned short f2bf(float f) {
    union { float f; unsigned u; } v; v.f = f;
    unsigned u = v.u;
    u += 0x7fffu + ((u >> 16) & 1u);   // RNE
    return (unsigned short)(u >> 16);
}
__device__ __forceinline__ float bf2f(unsigned short b) {
    union { unsigned u; float f; } v; v.u = ((unsigned)b) << 16;
    return v.f;
}
__device__ __forceinline__ float fast_exp2(float x) {
#if __has_builtin(__builtin_amdgcn_exp2f)
    return __builtin_amdgcn_exp2f(x);
#else
    return exp2f(x);
#endif
}
// async global->LDS, 16B per lane, LDS dest = wave-uniform base + lane*16
__device__ __forceinline__ void load_lds16(const void* g, void* l) {
    auto gp = (__attribute__((address_space(1))) unsigned int*)(uintptr_t)g;
    auto lp = (__attribute__((address_space(3))) unsigned int*)(uintptr_t)l;
    __builtin_amdgcn_global_load_lds(gp, lp, 16, 0, 0);
}

// ---------------- LayerNorm: fp32 in -> bf16 out ----------------
__global__ __launch_bounds__(256) void ln_kernel(const float* __restrict__ X,
        const float* __restrict__ g, const float* __restrict__ b,
        unsigned short* __restrict__ Xn) {
    const int row = blockIdx.x;
    const float* xr = X + (size_t)row * kDM;
    const float4 v0 = ((const float4*)xr)[threadIdx.x];
    const float4 v1 = ((const float4*)xr)[threadIdx.x + 256];
    float s  = v0.x + v0.y + v0.z + v0.w + v1.x + v1.y + v1.z + v1.w;
    float sq = v0.x*v0.x + v0.y*v0.y + v0.z*v0.z + v0.w*v0.w
             + v1.x*v1.x + v1.y*v1.y + v1.z*v1.z + v1.w*v1.w;
    #pragma unroll
    for (int m = 1; m < 64; m <<= 1) { s += __shfl_xor(s, m); sq += __shfl_xor(sq, m); }
    __shared__ float ls[4], lq[4];
    if ((threadIdx.x & 63) == 0) { ls[threadIdx.x >> 6] = s; lq[threadIdx.x >> 6] = sq; }
    __syncthreads();
    s  = ls[0] + ls[1] + ls[2] + ls[3];
    sq = lq[0] + lq[1] + lq[2] + lq[3];
    const float mu   = s * (1.0f / kDM);
    const float rstd = rsqrtf(sq * (1.0f / kDM) - mu * mu + 1e-5f);
    unsigned short* xo = Xn + (size_t)row * kDM;
    {
        const float4 gg = ((const float4*)g)[threadIdx.x];
        const float4 bb = ((const float4*)b)[threadIdx.x];
        ushort4 o;
        o.x = f2bf((v0.x - mu) * rstd * gg.x + bb.x);
        o.y = f2bf((v0.y - mu) * rstd * gg.y + bb.y);
        o.z = f2bf((v0.z - mu) * rstd * gg.z + bb.z);
        o.w = f2bf((v0.w - mu) * rstd * gg.w + bb.w);
        ((ushort4*)xo)[threadIdx.x] = o;
    }
    {
        const float4 gg = ((const float4*)g)[threadIdx.x + 256];
        const float4 bb = ((const float4*)b)[threadIdx.x + 256];
        ushort4 o;
        o.x = f2bf((v1.x - mu) * rstd * gg.x + bb.x);
        o.y = f2bf((v1.y - mu) * rstd * gg.y + bb.y);
        o.z = f2bf((v1.z - mu) * rstd * gg.z + bb.z);
        o.w = f2bf((v1.w - mu) * rstd * gg.w + bb.w);
        ((ushort4*)xo)[threadIdx.x + 256] = o;
    }
}

// ------------- weight transpose+cast: W[K][N] f32 -> Wt[N][K] bf16 -------------
__global__ __launch_bounds__(256) void wt_kernel(
        const float* __restrict__ W0, const float* __restrict__ W1,
        const float* __restrict__ W2, const float* __restrict__ W3,
        unsigned short* __restrict__ T0, unsigned short* __restrict__ T1,
        unsigned short* __restrict__ T2, unsigned short* __restrict__ T3) {
    const float* W; unsigned short* T;
    switch (blockIdx.z) {
        case 0:  W = W0; T = T0; break;
        case 1:  W = W1; T = T1; break;
        case 2:  W = W2; T = T2; break;
        default: W = W3; T = T3; break;
    }
    __shared__ float tile[32][33];
    const int tx = threadIdx.x & 31, ty = threadIdx.x >> 5;
    const int r0 = blockIdx.y * 32, c0 = blockIdx.x * 32;
    #pragma unroll
    for (int i = 0; i < 4; ++i)
        tile[ty + i * 8][tx] = W[(size_t)(r0 + ty + i * 8) * kDM + c0 + tx];
    __syncthreads();
    #pragma unroll
    for (int i = 0; i < 4; ++i)
        T[(size_t)(c0 + ty + i * 8) * kDM + r0 + tx] = f2bf(tile[tx][ty + i * 8]);
}

// --- bias concat: [bq|bk|bv] -> 6144 floats ---
__global__ __launch_bounds__(256) void bias_pack(const float* __restrict__ bq,
        const float* __restrict__ bk, const float* __restrict__ bv,
        float* __restrict__ o) {
    const int i = blockIdx.x * 256 + threadIdx.x;
    o[i] = (i < 2048) ? bq[i] : ((i < 4096) ? bk[i - 2048] : bv[i - 4096]);
}

// --- V transpose: [bh][s][dh] bf16 -> [bh][dh][s] bf16, 64x64 tiles ---
__global__ __launch_bounds__(256) void vtr_kernel(const unsigned short* __restrict__ Vin,
                                                  unsigned short* __restrict__ Vout) {
    __shared__ __align__(16) unsigned short tile[64 * 72];
    const int bhz = blockIdx.z;
    const int s0 = blockIdx.x * 64, d0 = blockIdx.y * 64;
    const int t = threadIdx.x;
    const unsigned short* src = Vin + ((size_t)bhz * kS + s0) * kDH + d0;
    #pragma unroll
    for (int i = 0; i < 2; ++i) {
        const int r = (t >> 3) + 32 * i;
        const int g = t & 7;
        *(uint4*)(tile + r * 72 + g * 8) = *(const uint4*)(src + (size_t)r * kDH + g * 8);
    }
    __syncthreads();
    unsigned short* dst = Vout + ((size_t)bhz * kDH + d0) * kS + s0;
    #pragma unroll
    for (int i = 0; i < 2; ++i) {
        const int d = (t >> 3) + 32 * i;
        const int sg = t & 7;
        union { unsigned short u[8]; uint4 v; } o;
        #pragma unroll
        for (int j = 0; j < 8; ++j)
            o.u[j] = tile[(sg * 8 + j) * 72 + d];
        *(uint4*)(dst + (size_t)d * kS + sg * 8) = o.v;
    }
}

// ------------- GEMM (legacy 128x128, m97 structure): out-proj only -------------
__global__ __launch_bounds__(256) void gemm_kernel(
        const unsigned short* __restrict__ A, const unsigned short* __restrict__ Bt,
        const float* __restrict__ bias, void* __restrict__ C0, void* __restrict__ C1,
        void* __restrict__ C2, const float scale0, const int fp32out) {
    __shared__ __align__(16) unsigned short ldsA[2][128 * 32];
    __shared__ __align__(16) unsigned short ldsB[2][128 * 32];
    const int m0 = blockIdx.x * 128, n0 = blockIdx.y * 128;
    const int tid = threadIdx.x, lane = tid & 63, w = tid >> 6;
    const int wm = (w >> 1) * 64, wn = (w & 1) * 64;
    const int quad = lane >> 4, l15 = lane & 15;
    f32x4 acc[4][4] = {};
    const int srow = lane >> 2, scol = (lane & 3) * 8;
    for (int k0 = 0; k0 < kDM; k0 += 64) {
        __syncthreads();
        #pragma unroll
        for (int sub = 0; sub < 2; ++sub) {
            #pragma unroll
            for (int i = 0; i < 2; ++i) {
                const int c = w + i * 4;
                const int row = c * 16 + srow;
                const int kc = k0 + sub * 32 + scol;
                load_lds16(A  + (size_t)(m0 + row) * kDM + kc, &ldsA[sub][c * 512]);
                load_lds16(Bt + (size_t)(n0 + row) * kDM + kc, &ldsB[sub][c * 512]);
            }
        }
        __syncthreads();
        #pragma unroll
        for (int sub = 0; sub < 2; ++sub) {
            bf16x8 af[4], bfr[4];
            #pragma unroll
            for (int mt = 0; mt < 4; ++mt)
                af[mt] = *(const bf16x8*)(&ldsA[sub][(wm + mt * 16 + l15) * 32 + quad * 8]);
            #pragma unroll
            for (int nt = 0; nt < 4; ++nt)
                bfr[nt] = *(const bf16x8*)(&ldsB[sub][(wn + nt * 16 + l15) * 32 + quad * 8]);
            #pragma unroll
            for (int mt = 0; mt < 4; ++mt)
                #pragma unroll
                for (int nt = 0; nt < 4; ++nt)
                    acc[mt][nt] = __builtin_amdgcn_mfma_f32_16x16x32_bf16(af[mt], bfr[nt], acc[mt][nt], 0, 0, 0);
        }
    }
    const int proj = n0 >> 11;
    void* Cb = (proj == 0) ? C0 : ((proj == 1) ? C1 : C2);
    const float scl = (proj == 0) ? scale0 : 1.0f;
    #pragma unroll
    for (int mt = 0; mt < 4; ++mt) {
        #pragma unroll
        for (int nt = 0; nt < 4; ++nt) {
            const int ng = n0 + wn + nt * 16 + l15;
            const float bv = bias[ng];
            const int col = ng & 2047;
            const int h = col >> 7, dh = col & 127;
            #pragma unroll
            for (int r = 0; r < 4; ++r) {
                const int mg = m0 + wm + mt * 16 + quad * 4 + r;
                const float val = (acc[mt][nt][r] + bv) * scl;
                if (fp32out) {
                    ((float*)Cb)[(size_t)mg * kDM + ng] = val;
                } else {
                    const int bb = mg >> 11, ss = mg & 2047;
                    ((unsigned short*)Cb)[((size_t)(bb * kNH + h) * kS + ss) * kDH + dh] = f2bf(val);
                }
            }
        }
    }
}

// ------------- GEMM 256x256, 8-wave, BK=64, 4-phase counted-vmcnt pipeline -----
// QKV projection only (bf16 scatter out). Schedule per K-tile t (buf = t&1):
//   ph1: read A-lo+B-lo frags; stage B-half1 of t+1 -> buf^1; bar; lgkm; 16 MFMA; bar
//   ph2: read B-hi;            stage A-half1 of t+1 -> buf^1; bar; lgkm; 16 MFMA; bar
//   ph3: read A-hi;            stage B-half0 of t+2 -> buf  ; bar; lgkm; 16 MFMA; bar
//   ph4: (regs only);          stage A-half0 of t+2 -> buf  ; bar; 16 MFMA; vmcnt(4); bar
// Race-freedom: each wave reads only A-half(wr) (last read ph3) and B-half(wc>>1)
// (last read ph2); every stage into a region is program-ordered after the barrier
// that closes that region's last read phase. Boundary vmcnt(4) leaves exactly the
// 2 newest half-tiles (t+2's B0,A0 = 4 loads) in flight; everything older --
// including all 4 halves of tile t+1 -- has landed (per-wave vmcnt + barrier =>
// cross-wave guarantee). LDS: 16B-granule XOR swizzle (phys colg = colg ^ (row&7)),
// applied on BOTH the global source (inverse) and the ds_read address (rule 21).
__global__ __launch_bounds__(512, 2) void gemm256_kernel(
        const unsigned short* __restrict__ A, const unsigned short* __restrict__ Bt,
        const float* __restrict__ bias, void* __restrict__ C0, void* __restrict__ C1,
        void* __restrict__ C2, const float scale0) {
    __shared__ __align__(16) unsigned short sA[2][2 * 128 * 64];
    __shared__ __align__(16) unsigned short sB[2][2 * 128 * 64];
    const int tid = threadIdx.x, lane = tid & 63, w = tid >> 6;
    const int quad = lane >> 4, l15 = lane & 15;
    const int wr = w >> 2, wc = w & 3;          // 2M x 4N wave grid
    const int m0 = blockIdx.x * 256, n0 = blockIdx.y * 256;
    // staging: one instruction = 8 rows x 128B; lane l -> row l>>3, phys col l&7,
    // so lane fetches logical granule (l&7) ^ (l>>3 & 7) of its row (inverse swz)
    const int srow = lane >> 3;
    const int scol = ((lane & 7) ^ srow) * 8;   // element offset within 64-k row
    size_t aOff[2], bOff[2]; int lOff[2];
    #pragma unroll
    for (int i = 0; i < 2; ++i) {
        const int wrow = (i * 8 + w) * 8 + srow;     // row within a 128-row half
        aOff[i] = (size_t)(m0 + wrow) * kDM + scol;  // + h*128*kDM + kt*64
        bOff[i] = (size_t)(n0 + wrow) * kDM + scol;
        lOff[i] = (i * 8 + w) * 512;                 // + h*8192 (elements)
    }
    const int swz = l15 & 7;
    int colq[2];
    #pragma unroll
    for (int ks = 0; ks < 2; ++ks) colq[ks] = ((ks * 4 + quad) ^ swz) * 8;

#define STG_A(buf, h, kt) { \
    load_lds16(A  + aOff[0] + (size_t)(h) * (128 * kDM) + (kt) * 64, &sA[buf][(h) * 8192 + lOff[0]]); \
    load_lds16(A  + aOff[1] + (size_t)(h) * (128 * kDM) + (kt) * 64, &sA[buf][(h) * 8192 + lOff[1]]); }
#define STG_B(buf, h, kt) { \
    load_lds16(Bt + bOff[0] + (size_t)(h) * (128 * kDM) + (kt) * 64, &sB[buf][(h) * 8192 + lOff[0]]); \
    load_lds16(Bt + bOff[1] + (size_t)(h) * (128 * kDM) + (kt) * 64, &sB[buf][(h) * 8192 + lOff[1]]); }

    f32x4 acc[8][4] = {};
    // prologue: tile0 (4 halves) + B0/A0 of tile1; wait 8 oldest, keep 4 in flight
    STG_A(0, 0, 0); STG_A(0, 1, 0);
    STG_B(0, 0, 0); STG_B(0, 1, 0);
    STG_B(1, 0, 1); STG_A(1, 0, 1);
    asm volatile("s_waitcnt vmcnt(4)" ::: "memory");
    __builtin_amdgcn_s_barrier();

    const int NT = kDM / 64;                    // 32 K-tiles
    bf16x8 af[4][2], bl[2][2], bh[2][2];
    for (int t = 0; t < NT; ++t) {
        const int cur = t & 1, nxt = cur ^ 1;
        // ---- phase 1: A-lo + B-lo reads; stage B1^{t+1}; mfma (m-lo x n-lo)
        #pragma unroll
        for (int mt = 0; mt < 4; ++mt)
            #pragma unroll
            for (int ks = 0; ks < 2; ++ks)
                af[mt][ks] = *(const bf16x8*)(&sA[cur][(wr * 128 + mt * 16 + l15) * 64 + colq[ks]]);
        #pragma unroll
        for (int nt = 0; nt < 2; ++nt)
            #pragma unroll
            for (int ks = 0; ks < 2; ++ks)
                bl[nt][ks] = *(const bf16x8*)(&sB[cur][(wc * 64 + nt * 16 + l15) * 64 + colq[ks]]);
        if (t + 1 < NT) STG_B(nxt, 1, t + 1);
        __builtin_amdgcn_s_barrier();
        asm volatile("s_waitcnt lgkmcnt(0)" ::: "memory");
        __builtin_amdgcn_s_setprio(1);
        #pragma unroll
        for (int mt = 0; mt < 4; ++mt)
            #pragma unroll
            for (int nt = 0; nt < 2; ++nt)
                #pragma unroll
                for (int ks = 0; ks < 2; ++ks)
                    acc[mt][nt] = __builtin_amdgcn_mfma_f32_16x16x32_bf16(af[mt][ks], bl[nt][ks], acc[mt][nt], 0, 0, 0);
        __builtin_amdgcn_s_setprio(0);
        __builtin_amdgcn_s_barrier();
        // ---- phase 2: B-hi reads; stage A1^{t+1}; mfma (m-lo x n-hi)
        #pragma unroll
        for (int nt = 0; nt < 2; ++nt)
            #pragma unroll
            for (int ks = 0; ks < 2; ++ks)
                bh[nt][ks] = *(const bf16x8*)(&sB[cur][(wc * 64 + 32 + nt * 16 + l15) * 64 + colq[ks]]);
        if (t + 1 < NT) STG_A(nxt, 1, t + 1);
        __builtin_amdgcn_s_barrier();
        asm volatile("s_waitcnt lgkmcnt(0)" ::: "memory");
        __builtin_amdgcn_s_setprio(1);
        #pragma unroll
        for (int mt = 0; mt < 4; ++mt)
            #pragma unroll
            for (int nt = 0; nt < 2; ++nt)
                #pragma unroll
                for (int ks = 0; ks < 2; ++ks)
                    acc[mt][2 + nt] = __builtin_amdgcn_mfma_f32_16x16x32_bf16(af[mt][ks], bh[nt][ks], acc[mt][2 + nt], 0, 0, 0);
        __builtin_amdgcn_s_setprio(0);
        __builtin_amdgcn_s_barrier();
        // ---- phase 3: A-hi reads (reuse af regs); stage B0^{t+2}; mfma (m-hi x n-hi)
        #pragma unroll
        for (int mt = 0; mt < 4; ++mt)
            #pragma unroll
            for (int ks = 0; ks < 2; ++ks)
                af[mt][ks] = *(const bf16x8*)(&sA[cur][(wr * 128 + 64 + mt * 16 + l15) * 64 + colq[ks]]);
        if (t + 2 < NT) STG_B(cur, 0, t + 2);
        __builtin_amdgcn_s_barrier();
        asm volatile("s_waitcnt lgkmcnt(0)" ::: "memory");
        __builtin_amdgcn_s_setprio(1);
        #pragma unroll
        for (int mt = 0; mt < 4; ++mt)
            #pragma unroll
            for (int nt = 0; nt < 2; ++nt)
                #pragma unroll
                for (int ks = 0; ks < 2; ++ks)
                    acc[4 + mt][2 + nt] = __builtin_amdgcn_mfma_f32_16x16x32_bf16(af[mt][ks], bh[nt][ks], acc[4 + mt][2 + nt], 0, 0, 0);
        __builtin_amdgcn_s_setprio(0);
        __builtin_amdgcn_s_barrier();
        // ---- phase 4: regs only; stage A0^{t+2}; mfma (m-hi x n-lo); boundary
        if (t + 2 < NT) STG_A(cur, 0, t + 2);
        __builtin_amdgcn_s_barrier();
        __builtin_amdgcn_s_setprio(1);
        #pragma unroll
        for (int mt = 0; mt < 4; ++mt)
            #pragma unroll
            for (int nt = 0; nt < 2; ++nt)
                #pragma unroll
                for (int ks = 0; ks < 2; ++ks)
                    acc[4 + mt][nt] = __builtin_amdgcn_mfma_f32_16x16x32_bf16(af[mt][ks], bl[nt][ks], acc[4 + mt][nt], 0, 0, 0);
        __builtin_amdgcn_s_setprio(0);
        if (t + 1 < NT) {
            if (t + 2 < NT) { asm volatile("s_waitcnt vmcnt(4)" ::: "memory"); }
            else            { asm volatile("s_waitcnt vmcnt(0)" ::: "memory"); }
            __builtin_amdgcn_s_barrier();
        }
    }
#undef STG_A
#undef STG_B
    // epilogue: bf16 scatter to [B,H,S,Dh]; scale on proj 0 (Q)
    const int proj = n0 >> 11;
    void* Cb = (proj == 0) ? C0 : ((proj == 1) ? C1 : C2);
    const float scl = (proj == 0) ? scale0 : 1.0f;
    #pragma unroll
    for (int mt = 0; mt < 8; ++mt) {
        #pragma unroll
        for (int nt = 0; nt < 4; ++nt) {
            const int ng = n0 + wc * 64 + nt * 16 + l15;
            const float bv = bias[ng];
            const int col = ng & 2047;
            const int h = col >> 7, dh = col & 127;
            #pragma unroll
            for (int r = 0; r < 4; ++r) {
                const int mg = m0 + wr * 128 + mt * 16 + quad * 4 + r;
                const float val = (acc[mt][nt][r] + bv) * scl;
                const int bb = mg >> 11, ss = mg & 2047;
                ((unsigned short*)Cb)[((size_t)(bb * kNH + h) * kS + ss) * kDH + dh] = f2bf(val);
            }
        }
    }
}

// ------------- causal flash attention, S^T form, paired q-tiles -------------
__global__ __launch_bounds__(256, 2) void attn_kernel(
        const unsigned short* __restrict__ Q, const unsigned short* __restrict__ Kk,
        const unsigned short* __restrict__ Vt, unsigned short* __restrict__ AV) {
    __shared__ __align__(16) unsigned short ldsK[2][64 * 128];   // swizzled [key][d]
    __shared__ __align__(16) unsigned short ldsV[2][128 * 64];   // swizzled [d][key]
    __shared__ __align__(16) unsigned short ldsP[4 * 16 * 64];   // per-wave swizzled [q][key]
    const int bh = blockIdx.x, pr = blockIdx.y;
    const unsigned short* Qb = Q  + (size_t)bh * kS * kDH;
    const unsigned short* Kb = Kk + (size_t)bh * kS * kDH;
    const unsigned short* Vb = Vt + (size_t)bh * kDH * kS;
    const int tid = threadIdx.x, lane = tid & 63, w = tid >> 6;
    const int quad = lane >> 4, l15 = lane & 15;
    int kSrc[4], vSrc[4], ldst[4];
    #pragma unroll
    for (int i = 0; i < 4; ++i) {
        const int c = w * 4 + i;
        const int rK = c * 4 + (lane >> 4);
        const int gK = (lane & 15) ^ (rK & 15);
        kSrc[i] = rK * kDH + gK * 8;
        const int dV = c * 8 + (lane >> 3);
        const int gV = (lane & 7) ^ (dV & 7);
        vSrc[i] = dV * kS + gV * 8;
        ldst[i] = c * 512;
    }
    unsigned short* pw = ldsP + w * 1024;
    const int pswz = 2 * (l15 & 7);
    const int bb = bh >> 4, h = bh & 15;
    for (int half = 0; half < 2; ++half) {
        const int qt = half ? (31 - pr) : pr;
        const int qrow0 = qt * 64 + w * 16;
        bf16x8 qf[4];
        #pragma unroll
        for (int kk = 0; kk < 4; ++kk)
            qf[kk] = *(const bf16x8*)(Qb + (size_t)(qrow0 + l15) * kDH + kk * 32 + quad * 8);
        f32x4 accO[8] = {};
        float mrun = -3.0e38f, lrun = 0.0f;
        #pragma unroll
        for (int i = 0; i < 4; ++i) {
            load_lds16(Kb + kSrc[i], &ldsK[0][ldst[i]]);
            load_lds16(Vb + vSrc[i], &ldsV[0][ldst[i]]);
        }
        __syncthreads();
        int cur = 0;
        for (int kt = 0; kt <= qt; ++kt) {
            if (kt < qt) {
                #pragma unroll
                for (int i = 0; i < 4; ++i) {
                    load_lds16(Kb + (size_t)(kt + 1) * (64 * kDH) + kSrc[i], &ldsK[cur ^ 1][ldst[i]]);
                    load_lds16(Vb + (kt + 1) * 64 + vSrc[i], &ldsV[cur ^ 1][ldst[i]]);
                }
            }
            f32x4 accS[4] = {};
            #pragma unroll
            for (int kk = 0; kk < 4; ++kk) {
                bf16x8 kf[4];
                #pragma unroll
                for (int mt = 0; mt < 4; ++mt)
                    kf[mt] = *(const bf16x8*)(&ldsK[cur][(mt * 16 + l15) * 128 + (((kk * 4 + quad) ^ l15) << 3)]);
                #pragma unroll
                for (int mt = 0; mt < 4; ++mt)
                    accS[mt] = __builtin_amdgcn_mfma_f32_16x16x32_bf16(kf[mt], qf[kk], accS[mt], 0, 0, 0);
            }
            if (kt == qt) {
                const int ql = w * 16 + l15;
                #pragma unroll
                for (int mt = 0; mt < 4; ++mt)
                    #pragma unroll
                    for (int r = 0; r < 4; ++r)
                        if (mt * 16 + quad * 4 + r > ql) accS[mt][r] = -3.0e38f;
            }
            float mx = accS[0][0];
            #pragma unroll
            for (int mt = 0; mt < 4; ++mt)
                #pragma unroll
                for (int r = 0; r < 4; ++r) mx = fmaxf(mx, accS[mt][r]);
            mx = fmaxf(mx, __shfl_xor(mx, 16));
            mx = fmaxf(mx, __shfl_xor(mx, 32));
            const float mnew = fmaxf(mrun, mx);
            const float al = fast_exp2(mrun - mnew);
            float rs = 0.f;
            #pragma unroll
            for (int mt = 0; mt < 4; ++mt) {
                ushort4 pk;
                unsigned short* pe = (unsigned short*)&pk;
                #pragma unroll
                for (int r = 0; r < 4; ++r) {
                    const float p = fast_exp2(accS[mt][r] - mnew);
                    const unsigned short pb = f2bf(p);
                    pe[r] = pb;
                    rs += bf2f(pb);
                }
                *(ushort4*)(pw + l15 * 64 + (((mt * 4 + quad) ^ pswz) << 2)) = pk;
            }
            rs += __shfl_xor(rs, 16);
            rs += __shfl_xor(rs, 32);
            lrun = lrun * al + rs;
            mrun = mnew;
            float albr[4];
            #pragma unroll
            for (int r = 0; r < 4; ++r)
                albr[r] = __shfl(al, (lane & 48) | (quad << 2) | r);
            #pragma unroll
            for (int dt = 0; dt < 8; ++dt)
                #pragma unroll
                for (int r = 0; r < 4; ++r)
                    accO[dt][r] *= albr[r];
            asm volatile("s_waitcnt lgkmcnt(0)" ::: "memory");
            #pragma unroll
            for (int kk = 0; kk < 2; ++kk) {
                const bf16x8 pa = *(const bf16x8*)(pw + l15 * 64 + (((kk * 8 + quad * 2) ^ pswz) << 2));
                #pragma unroll
                for (int dt = 0; dt < 8; ++dt) {
                    const bf16x8 vf = *(const bf16x8*)(&ldsV[cur][(dt * 16 + l15) * 64 + (((kk * 4 + quad) ^ (l15 & 7)) << 3)]);
                    accO[dt] = __builtin_amdgcn_mfma_f32_16x16x32_bf16(pa, vf, accO[dt], 0, 0, 0);
                }
            }
            __syncthreads();
            cur ^= 1;
        }
        float linv[4];
        #pragma unroll
        for (int r = 0; r < 4; ++r)
            linv[r] = __shfl(lrun, (lane & 48) | (quad << 2) | r);
        #pragma unroll
        for (int r = 0; r < 4; ++r) {
            const float inv = 1.0f / linv[r];
            unsigned short* orow = AV + ((size_t)bb * kS + qrow0 + quad * 4 + r) * kDM + h * kDH;
            #pragma unroll
            for (int dt = 0; dt < 8; ++dt)
                orow[dt * 16 + l15] = f2bf(accO[dt][r] * inv);
        }
    }
}

extern "C" void kernel_launch(void* const* d_in, const int* in_sizes, int n_in,
                              void* d_out, int out_size, void* d_ws, size_t ws_size,
                              hipStream_t stream) {
    const float* X   = (const float*)d_in[0];
    const float* lng = (const float*)d_in[1];
    const float* lnb = (const float*)d_in[2];
    const float* Wq  = (const float*)d_in[3];
    const float* bq  = (const float*)d_in[4];
    const float* Wk  = (const float*)d_in[5];
    const float* bk  = (const float*)d_in[6];
    const float* Wv  = (const float*)d_in[7];
    const float* bv  = (const float*)d_in[8];
    const float* Wo  = (const float*)d_in[9];
    const float* bo  = (const float*)d_in[10];
    float* out = (float*)d_out;

    char* p = (char*)d_ws;
    unsigned short* Xn  = (unsigned short*)p; p += (size_t)kM * kDM * 2;
    unsigned short* Wqt = (unsigned short*)p; p += (size_t)kDM * kDM * 2;  // Wq|Wk|Wv contiguous
    unsigned short* Wkt = (unsigned short*)p; p += (size_t)kDM * kDM * 2;
    unsigned short* Wvt = (unsigned short*)p; p += (size_t)kDM * kDM * 2;
    unsigned short* Wot = (unsigned short*)p; p += (size_t)kDM * kDM * 2;
    unsigned short* Qb  = (unsigned short*)p; p += (size_t)kM * kDM * 2;
    unsigned short* Kb  = (unsigned short*)p; p += (size_t)kM * kDM * 2;
    unsigned short* Vtb = (unsigned short*)p; p += (size_t)kM * kDM * 2;
    unsigned short* AV  = (unsigned short*)p; p += (size_t)kM * kDM * 2;
    unsigned short* Vtmp = AV;        // alias: consumed by vtr before attn writes AV
    float* biasc = (float*)Vtb;       // alias: consumed by qkv-gemm before vtr writes Vtb

    const float qscale = 0.08838834764831845f * 1.4426950408889634f;

    ln_kernel<<<dim3(kM), dim3(256), 0, stream>>>(X, lng, lnb, Xn);
    wt_kernel<<<dim3(64, 64, 4), dim3(256), 0, stream>>>(Wq, Wk, Wv, Wo, Wqt, Wkt, Wvt, Wot);
    bias_pack<<<dim3(24), dim3(256), 0, stream>>>(bq, bk, bv, biasc);
    // fused QKV GEMM: 256x256 8-wave counted-vmcnt pipeline; N=6144 over [Wqt|Wkt|Wvt]
    gemm256_kernel<<<dim3(16, 24), dim3(512), 0, stream>>>(Xn, Wqt, biasc, Qb, Kb, Vtmp, qscale);
    vtr_kernel<<<dim3(32, 2, 32), dim3(256), 0, stream>>>(Vtmp, Vtb);
    attn_kernel<<<dim3(32, 16), dim3(256), 0, stream>>>(Qb, Kb, Vtb, AV);
    gemm_kernel<<<dim3(32, 16), dim3(256), 0, stream>>>(AV, Wot, bo, out, out, out, 1.0f, 1);
}

// Round 3
// 384.359 us; speedup vs baseline: 1.0282x; 1.0095x over previous
//
#include <hip/hip_runtime.h>
#include <cstdint>

constexpr int kDM = 2048;   // d_model
constexpr int kNH = 16;     // heads
constexpr int kDH = 128;    // head dim
constexpr int kS  = 2048;   // seq
constexpr int kM  = 4096;   // B*S rows

typedef __bf16 bf16x8 __attribute__((ext_vector_type(8)));
typedef float  f32x4  __attribute__((ext_vector_type(4)));

__device__ __forceinline__ unsigned short f2bf(float f) {
    union { float f; unsigned u; } v; v.f = f;
    unsigned u = v.u;
    u += 0x7fffu + ((u >> 16) & 1u);   // RNE
    return (unsigned short)(u >> 16);
}
__device__ __forceinline__ float bf2f(unsigned short b) {
    union { unsigned u; float f; } v; v.u = ((unsigned)b) << 16;
    return v.f;
}
__device__ __forceinline__ float fast_exp2(float x) {
#if __has_builtin(__builtin_amdgcn_exp2f)
    return __builtin_amdgcn_exp2f(x);
#else
    return exp2f(x);
#endif
}
// async global->LDS, 16B per lane, LDS dest = wave-uniform base + lane*16
__device__ __forceinline__ void load_lds16(const void* g, void* l) {
    auto gp = (__attribute__((address_space(1))) unsigned int*)(uintptr_t)g;
    auto lp = (__attribute__((address_space(3))) unsigned int*)(uintptr_t)l;
    __builtin_amdgcn_global_load_lds(gp, lp, 16, 0, 0);
}

// ---------------- LayerNorm: fp32 in -> bf16 out ----------------
__global__ __launch_bounds__(256) void ln_kernel(const float* __restrict__ X,
        const float* __restrict__ g, const float* __restrict__ b,
        unsigned short* __restrict__ Xn) {
    const int row = blockIdx.x;
    const float* xr = X + (size_t)row * kDM;
    const float4 v0 = ((const float4*)xr)[threadIdx.x];
    const float4 v1 = ((const float4*)xr)[threadIdx.x + 256];
    float s  = v0.x + v0.y + v0.z + v0.w + v1.x + v1.y + v1.z + v1.w;
    float sq = v0.x*v0.x + v0.y*v0.y + v0.z*v0.z + v0.w*v0.w
             + v1.x*v1.x + v1.y*v1.y + v1.z*v1.z + v1.w*v1.w;
    #pragma unroll
    for (int m = 1; m < 64; m <<= 1) { s += __shfl_xor(s, m); sq += __shfl_xor(sq, m); }
    __shared__ float ls[4], lq[4];
    if ((threadIdx.x & 63) == 0) { ls[threadIdx.x >> 6] = s; lq[threadIdx.x >> 6] = sq; }
    __syncthreads();
    s  = ls[0] + ls[1] + ls[2] + ls[3];
    sq = lq[0] + lq[1] + lq[2] + lq[3];
    const float mu   = s * (1.0f / kDM);
    const float rstd = rsqrtf(sq * (1.0f / kDM) - mu * mu + 1e-5f);
    unsigned short* xo = Xn + (size_t)row * kDM;
    {
        const float4 gg = ((const float4*)g)[threadIdx.x];
        const float4 bb = ((const float4*)b)[threadIdx.x];
        ushort4 o;
        o.x = f2bf((v0.x - mu) * rstd * gg.x + bb.x);
        o.y = f2bf((v0.y - mu) * rstd * gg.y + bb.y);
        o.z = f2bf((v0.z - mu) * rstd * gg.z + bb.z);
        o.w = f2bf((v0.w - mu) * rstd * gg.w + bb.w);
        ((ushort4*)xo)[threadIdx.x] = o;
    }
    {
        const float4 gg = ((const float4*)g)[threadIdx.x + 256];
        const float4 bb = ((const float4*)b)[threadIdx.x + 256];
        ushort4 o;
        o.x = f2bf((v1.x - mu) * rstd * gg.x + bb.x);
        o.y = f2bf((v1.y - mu) * rstd * gg.y + bb.y);
        o.z = f2bf((v1.z - mu) * rstd * gg.z + bb.z);
        o.w = f2bf((v1.w - mu) * rstd * gg.w + bb.w);
        ((ushort4*)xo)[threadIdx.x + 256] = o;
    }
}

// ------------- weight transpose+cast: W[K][N] f32 -> Wt[N][K] bf16 -------------
// R(this): 64x64 tiles; float4 global reads, odd-stride(65) LDS (scalar st/ld,
// 2-way bank alias = free), 16B coalesced uint4 stores (old version wrote 2B/lane
// in 64B segments -> half-rate writes on ~100MB of traffic).
__global__ __launch_bounds__(256) void wt_kernel(
        const float* __restrict__ W0, const float* __restrict__ W1,
        const float* __restrict__ W2, const float* __restrict__ W3,
        unsigned short* __restrict__ T0, unsigned short* __restrict__ T1,
        unsigned short* __restrict__ T2, unsigned short* __restrict__ T3) {
    const float* W; unsigned short* T;
    switch (blockIdx.z) {
        case 0:  W = W0; T = T0; break;
        case 1:  W = W1; T = T1; break;
        case 2:  W = W2; T = T2; break;
        default: W = W3; T = T3; break;
    }
    __shared__ float tile[64][65];
    const int t = threadIdx.x;
    const int r0 = blockIdx.y * 64, c0 = blockIdx.x * 64;
    const int lr = t >> 4, lc = (t & 15) * 4;
    #pragma unroll
    for (int i = 0; i < 4; ++i) {
        const float4 v = *(const float4*)&W[(size_t)(r0 + lr + i * 16) * kDM + c0 + lc];
        float* tp = &tile[lr + i * 16][lc];
        tp[0] = v.x; tp[1] = v.y; tp[2] = v.z; tp[3] = v.w;
    }
    __syncthreads();
    const int g = t & 7;
    #pragma unroll
    for (int j = 0; j < 2; ++j) {
        const int orr = (t >> 3) + j * 32;
        union { unsigned short u[8]; uint4 v; } o;
        #pragma unroll
        for (int jj = 0; jj < 8; ++jj)
            o.u[jj] = f2bf(tile[g * 8 + jj][orr]);
        *(uint4*)&T[(size_t)(c0 + orr) * kDM + r0 + g * 8] = o.v;
    }
}

// --- bias concat: [bq|bk|bv] -> 6144 floats ---
__global__ __launch_bounds__(256) void bias_pack(const float* __restrict__ bq,
        const float* __restrict__ bk, const float* __restrict__ bv,
        float* __restrict__ o) {
    const int i = blockIdx.x * 256 + threadIdx.x;
    o[i] = (i < 2048) ? bq[i] : ((i < 4096) ? bk[i - 2048] : bv[i - 4096]);
}

// --- V transpose: [bh][s][dh] bf16 -> [bh][dh][s] bf16, 64x64 tiles ---
__global__ __launch_bounds__(256) void vtr_kernel(const unsigned short* __restrict__ Vin,
                                                  unsigned short* __restrict__ Vout) {
    __shared__ __align__(16) unsigned short tile[64 * 72];
    const int bhz = blockIdx.z;
    const int s0 = blockIdx.x * 64, d0 = blockIdx.y * 64;
    const int t = threadIdx.x;
    const unsigned short* src = Vin + ((size_t)bhz * kS + s0) * kDH + d0;
    #pragma unroll
    for (int i = 0; i < 2; ++i) {
        const int r = (t >> 3) + 32 * i;
        const int g = t & 7;
        *(uint4*)(tile + r * 72 + g * 8) = *(const uint4*)(src + (size_t)r * kDH + g * 8);
    }
    __syncthreads();
    unsigned short* dst = Vout + ((size_t)bhz * kDH + d0) * kS + s0;
    #pragma unroll
    for (int i = 0; i < 2; ++i) {
        const int d = (t >> 3) + 32 * i;
        const int sg = t & 7;
        union { unsigned short u[8]; uint4 v; } o;
        #pragma unroll
        for (int j = 0; j < 8; ++j)
            o.u[j] = tile[(sg * 8 + j) * 72 + d];
        *(uint4*)(dst + (size_t)d * kS + sg * 8) = o.v;
    }
}

// ------------- GEMM (legacy 128x128, m97 structure): out-proj only -------------
// R(this): + XCD-chunked blockIdx swizzle (grid 512, 512%8==0 -> bijective).
__global__ __launch_bounds__(256) void gemm_kernel(
        const unsigned short* __restrict__ A, const unsigned short* __restrict__ Bt,
        const float* __restrict__ bias, void* __restrict__ C0, void* __restrict__ C1,
        void* __restrict__ C2, const float scale0, const int fp32out) {
    __shared__ __align__(16) unsigned short ldsA[2][128 * 32];
    __shared__ __align__(16) unsigned short ldsB[2][128 * 32];
    const int nwg = gridDim.x * gridDim.y;
    const int wg  = blockIdx.y * gridDim.x + blockIdx.x;
    const int cpx = nwg >> 3;
    const int swg = (wg & 7) * cpx + (wg >> 3);
    const int m0 = (swg % gridDim.x) * 128, n0 = (swg / gridDim.x) * 128;
    const int tid = threadIdx.x, lane = tid & 63, w = tid >> 6;
    const int wm = (w >> 1) * 64, wn = (w & 1) * 64;
    const int quad = lane >> 4, l15 = lane & 15;
    f32x4 acc[4][4] = {};
    const int srow = lane >> 2, scol = (lane & 3) * 8;
    for (int k0 = 0; k0 < kDM; k0 += 64) {
        __syncthreads();
        #pragma unroll
        for (int sub = 0; sub < 2; ++sub) {
            #pragma unroll
            for (int i = 0; i < 2; ++i) {
                const int c = w + i * 4;
                const int row = c * 16 + srow;
                const int kc = k0 + sub * 32 + scol;
                load_lds16(A  + (size_t)(m0 + row) * kDM + kc, &ldsA[sub][c * 512]);
                load_lds16(Bt + (size_t)(n0 + row) * kDM + kc, &ldsB[sub][c * 512]);
            }
        }
        __syncthreads();
        #pragma unroll
        for (int sub = 0; sub < 2; ++sub) {
            bf16x8 af[4], bfr[4];
            #pragma unroll
            for (int mt = 0; mt < 4; ++mt)
                af[mt] = *(const bf16x8*)(&ldsA[sub][(wm + mt * 16 + l15) * 32 + quad * 8]);
            #pragma unroll
            for (int nt = 0; nt < 4; ++nt)
                bfr[nt] = *(const bf16x8*)(&ldsB[sub][(wn + nt * 16 + l15) * 32 + quad * 8]);
            #pragma unroll
            for (int mt = 0; mt < 4; ++mt)
                #pragma unroll
                for (int nt = 0; nt < 4; ++nt)
                    acc[mt][nt] = __builtin_amdgcn_mfma_f32_16x16x32_bf16(af[mt], bfr[nt], acc[mt][nt], 0, 0, 0);
        }
    }
    const int proj = n0 >> 11;
    void* Cb = (proj == 0) ? C0 : ((proj == 1) ? C1 : C2);
    const float scl = (proj == 0) ? scale0 : 1.0f;
    #pragma unroll
    for (int mt = 0; mt < 4; ++mt) {
        #pragma unroll
        for (int nt = 0; nt < 4; ++nt) {
            const int ng = n0 + wn + nt * 16 + l15;
            const float bv = bias[ng];
            const int col = ng & 2047;
            const int h = col >> 7, dh = col & 127;
            #pragma unroll
            for (int r = 0; r < 4; ++r) {
                const int mg = m0 + wm + mt * 16 + quad * 4 + r;
                const float val = (acc[mt][nt][r] + bv) * scl;
                if (fp32out) {
                    ((float*)Cb)[(size_t)mg * kDM + ng] = val;
                } else {
                    const int bb = mg >> 11, ss = mg & 2047;
                    ((unsigned short*)Cb)[((size_t)(bb * kNH + h) * kS + ss) * kDH + dh] = f2bf(val);
                }
            }
        }
    }
}

// ------------- GEMM 256x256, 8-wave, BK=64, 4-phase counted-vmcnt pipeline -----
// (structure unchanged from R2 -- proven correct, 846 TF, 0 bank conflicts)
// R(this): + XCD-chunked blockIdx swizzle (grid 384, 384%8==0 -> bijective;
// each XCD gets 48 consecutive tiles = 3 B-panels (3MB, fits 4MB L2) x 16 m).
__global__ __launch_bounds__(512, 2) void gemm256_kernel(
        const unsigned short* __restrict__ A, const unsigned short* __restrict__ Bt,
        const float* __restrict__ bias, void* __restrict__ C0, void* __restrict__ C1,
        void* __restrict__ C2, const float scale0) {
    __shared__ __align__(16) unsigned short sA[2][2 * 128 * 64];
    __shared__ __align__(16) unsigned short sB[2][2 * 128 * 64];
    const int tid = threadIdx.x, lane = tid & 63, w = tid >> 6;
    const int quad = lane >> 4, l15 = lane & 15;
    const int wr = w >> 2, wc = w & 3;          // 2M x 4N wave grid
    const int nwg = gridDim.x * gridDim.y;
    const int wg  = blockIdx.y * gridDim.x + blockIdx.x;
    const int cpx = nwg >> 3;
    const int swg = (wg & 7) * cpx + (wg >> 3);
    const int m0 = (swg % gridDim.x) * 256, n0 = (swg / gridDim.x) * 256;
    const int srow = lane >> 3;
    const int scol = ((lane & 7) ^ srow) * 8;   // inverse-swizzled global source
    size_t aOff[2], bOff[2]; int lOff[2];
    #pragma unroll
    for (int i = 0; i < 2; ++i) {
        const int wrow = (i * 8 + w) * 8 + srow;     // row within a 128-row half
        aOff[i] = (size_t)(m0 + wrow) * kDM + scol;  // + h*128*kDM + kt*64
        bOff[i] = (size_t)(n0 + wrow) * kDM + scol;
        lOff[i] = (i * 8 + w) * 512;                 // + h*8192 (elements)
    }
    const int swz = l15 & 7;
    int colq[2];
    #pragma unroll
    for (int ks = 0; ks < 2; ++ks) colq[ks] = ((ks * 4 + quad) ^ swz) * 8;

#define STG_A(buf, h, kt) { \
    load_lds16(A  + aOff[0] + (size_t)(h) * (128 * kDM) + (kt) * 64, &sA[buf][(h) * 8192 + lOff[0]]); \
    load_lds16(A  + aOff[1] + (size_t)(h) * (128 * kDM) + (kt) * 64, &sA[buf][(h) * 8192 + lOff[1]]); }
#define STG_B(buf, h, kt) { \
    load_lds16(Bt + bOff[0] + (size_t)(h) * (128 * kDM) + (kt) * 64, &sB[buf][(h) * 8192 + lOff[0]]); \
    load_lds16(Bt + bOff[1] + (size_t)(h) * (128 * kDM) + (kt) * 64, &sB[buf][(h) * 8192 + lOff[1]]); }

    f32x4 acc[8][4] = {};
    STG_A(0, 0, 0); STG_A(0, 1, 0);
    STG_B(0, 0, 0); STG_B(0, 1, 0);
    STG_B(1, 0, 1); STG_A(1, 0, 1);
    asm volatile("s_waitcnt vmcnt(4)" ::: "memory");
    __builtin_amdgcn_s_barrier();

    const int NT = kDM / 64;                    // 32 K-tiles
    bf16x8 af[4][2], bl[2][2], bh[2][2];
    for (int t = 0; t < NT; ++t) {
        const int cur = t & 1, nxt = cur ^ 1;
        // ---- phase 1: A-lo + B-lo reads; stage B1^{t+1}; mfma (m-lo x n-lo)
        #pragma unroll
        for (int mt = 0; mt < 4; ++mt)
            #pragma unroll
            for (int ks = 0; ks < 2; ++ks)
                af[mt][ks] = *(const bf16x8*)(&sA[cur][(wr * 128 + mt * 16 + l15) * 64 + colq[ks]]);
        #pragma unroll
        for (int nt = 0; nt < 2; ++nt)
            #pragma unroll
            for (int ks = 0; ks < 2; ++ks)
                bl[nt][ks] = *(const bf16x8*)(&sB[cur][(wc * 64 + nt * 16 + l15) * 64 + colq[ks]]);
        if (t + 1 < NT) STG_B(nxt, 1, t + 1);
        __builtin_amdgcn_s_barrier();
        asm volatile("s_waitcnt lgkmcnt(0)" ::: "memory");
        __builtin_amdgcn_s_setprio(1);
        #pragma unroll
        for (int mt = 0; mt < 4; ++mt)
            #pragma unroll
            for (int nt = 0; nt < 2; ++nt)
                #pragma unroll
                for (int ks = 0; ks < 2; ++ks)
                    acc[mt][nt] = __builtin_amdgcn_mfma_f32_16x16x32_bf16(af[mt][ks], bl[nt][ks], acc[mt][nt], 0, 0, 0);
        __builtin_amdgcn_s_setprio(0);
        __builtin_amdgcn_s_barrier();
        // ---- phase 2: B-hi reads; stage A1^{t+1}; mfma (m-lo x n-hi)
        #pragma unroll
        for (int nt = 0; nt < 2; ++nt)
            #pragma unroll
            for (int ks = 0; ks < 2; ++ks)
                bh[nt][ks] = *(const bf16x8*)(&sB[cur][(wc * 64 + 32 + nt * 16 + l15) * 64 + colq[ks]]);
        if (t + 1 < NT) STG_A(nxt, 1, t + 1);
        __builtin_amdgcn_s_barrier();
        asm volatile("s_waitcnt lgkmcnt(0)" ::: "memory");
        __builtin_amdgcn_s_setprio(1);
        #pragma unroll
        for (int mt = 0; mt < 4; ++mt)
            #pragma unroll
            for (int nt = 0; nt < 2; ++nt)
                #pragma unroll
                for (int ks = 0; ks < 2; ++ks)
                    acc[mt][2 + nt] = __builtin_amdgcn_mfma_f32_16x16x32_bf16(af[mt][ks], bh[nt][ks], acc[mt][2 + nt], 0, 0, 0);
        __builtin_amdgcn_s_setprio(0);
        __builtin_amdgcn_s_barrier();
        // ---- phase 3: A-hi reads (reuse af regs); stage B0^{t+2}; mfma (m-hi x n-hi)
        #pragma unroll
        for (int mt = 0; mt < 4; ++mt)
            #pragma unroll
            for (int ks = 0; ks < 2; ++ks)
                af[mt][ks] = *(const bf16x8*)(&sA[cur][(wr * 128 + 64 + mt * 16 + l15) * 64 + colq[ks]]);
        if (t + 2 < NT) STG_B(cur, 0, t + 2);
        __builtin_amdgcn_s_barrier();
        asm volatile("s_waitcnt lgkmcnt(0)" ::: "memory");
        __builtin_amdgcn_s_setprio(1);
        #pragma unroll
        for (int mt = 0; mt < 4; ++mt)
            #pragma unroll
            for (int nt = 0; nt < 2; ++nt)
                #pragma unroll
                for (int ks = 0; ks < 2; ++ks)
                    acc[4 + mt][2 + nt] = __builtin_amdgcn_mfma_f32_16x16x32_bf16(af[mt][ks], bh[nt][ks], acc[4 + mt][2 + nt], 0, 0, 0);
        __builtin_amdgcn_s_setprio(0);
        __builtin_amdgcn_s_barrier();
        // ---- phase 4: regs only; stage A0^{t+2}; mfma (m-hi x n-lo); boundary
        if (t + 2 < NT) STG_A(cur, 0, t + 2);
        __builtin_amdgcn_s_barrier();
        __builtin_amdgcn_s_setprio(1);
        #pragma unroll
        for (int mt = 0; mt < 4; ++mt)
            #pragma unroll
            for (int nt = 0; nt < 2; ++nt)
                #pragma unroll
                for (int ks = 0; ks < 2; ++ks)
                    acc[4 + mt][nt] = __builtin_amdgcn_mfma_f32_16x16x32_bf16(af[mt][ks], bl[nt][ks], acc[4 + mt][nt], 0, 0, 0);
        __builtin_amdgcn_s_setprio(0);
        if (t + 1 < NT) {
            if (t + 2 < NT) { asm volatile("s_waitcnt vmcnt(4)" ::: "memory"); }
            else            { asm volatile("s_waitcnt vmcnt(0)" ::: "memory"); }
            __builtin_amdgcn_s_barrier();
        }
    }
#undef STG_A
#undef STG_B
    const int proj = n0 >> 11;
    void* Cb = (proj == 0) ? C0 : ((proj == 1) ? C1 : C2);
    const float scl = (proj == 0) ? scale0 : 1.0f;
    #pragma unroll
    for (int mt = 0; mt < 8; ++mt) {
        #pragma unroll
        for (int nt = 0; nt < 4; ++nt) {
            const int ng = n0 + wc * 64 + nt * 16 + l15;
            const float bv = bias[ng];
            const int col = ng & 2047;
            const int h = col >> 7, dh = col & 127;
            #pragma unroll
            for (int r = 0; r < 4; ++r) {
                const int mg = m0 + wr * 128 + mt * 16 + quad * 4 + r;
                const float val = (acc[mt][nt][r] + bv) * scl;
                const int bb = mg >> 11, ss = mg & 2047;
                ((unsigned short*)Cb)[((size_t)(bb * kNH + h) * kS + ss) * kDH + dh] = f2bf(val);
            }
        }
    }
}

// ------------- causal flash attention, S^T form, paired q-tiles -------------
__global__ __launch_bounds__(256, 2) void attn_kernel(
        const unsigned short* __restrict__ Q, const unsigned short* __restrict__ Kk,
        const unsigned short* __restrict__ Vt, unsigned short* __restrict__ AV) {
    __shared__ __align__(16) unsigned short ldsK[2][64 * 128];   // swizzled [key][d]
    __shared__ __align__(16) unsigned short ldsV[2][128 * 64];   // swizzled [d][key]
    __shared__ __align__(16) unsigned short ldsP[4 * 16 * 64];   // per-wave swizzled [q][key]
    const int bh = blockIdx.x, pr = blockIdx.y;
    const unsigned short* Qb = Q  + (size_t)bh * kS * kDH;
    const unsigned short* Kb = Kk + (size_t)bh * kS * kDH;
    const unsigned short* Vb = Vt + (size_t)bh * kDH * kS;
    const int tid = threadIdx.x, lane = tid & 63, w = tid >> 6;
    const int quad = lane >> 4, l15 = lane & 15;
    int kSrc[4], vSrc[4], ldst[4];
    #pragma unroll
    for (int i = 0; i < 4; ++i) {
        const int c = w * 4 + i;
        const int rK = c * 4 + (lane >> 4);
        const int gK = (lane & 15) ^ (rK & 15);
        kSrc[i] = rK * kDH + gK * 8;
        const int dV = c * 8 + (lane >> 3);
        const int gV = (lane & 7) ^ (dV & 7);
        vSrc[i] = dV * kS + gV * 8;
        ldst[i] = c * 512;
    }
    unsigned short* pw = ldsP + w * 1024;
    const int pswz = 2 * (l15 & 7);
    const int bb = bh >> 4, h = bh & 15;
    for (int half = 0; half < 2; ++half) {
        const int qt = half ? (31 - pr) : pr;
        const int qrow0 = qt * 64 + w * 16;
        bf16x8 qf[4];
        #pragma unroll
        for (int kk = 0; kk < 4; ++kk)
            qf[kk] = *(const bf16x8*)(Qb + (size_t)(qrow0 + l15) * kDH + kk * 32 + quad * 8);
        f32x4 accO[8] = {};
        float mrun = -3.0e38f, lrun = 0.0f;
        #pragma unroll
        for (int i = 0; i < 4; ++i) {
            load_lds16(Kb + kSrc[i], &ldsK[0][ldst[i]]);
            load_lds16(Vb + vSrc[i], &ldsV[0][ldst[i]]);
        }
        __syncthreads();
        int cur = 0;
        for (int kt = 0; kt <= qt; ++kt) {
            if (kt < qt) {
                #pragma unroll
                for (int i = 0; i < 4; ++i) {
                    load_lds16(Kb + (size_t)(kt + 1) * (64 * kDH) + kSrc[i], &ldsK[cur ^ 1][ldst[i]]);
                    load_lds16(Vb + (kt + 1) * 64 + vSrc[i], &ldsV[cur ^ 1][ldst[i]]);
                }
            }
            f32x4 accS[4] = {};
            #pragma unroll
            for (int kk = 0; kk < 4; ++kk) {
                bf16x8 kf[4];
                #pragma unroll
                for (int mt = 0; mt < 4; ++mt)
                    kf[mt] = *(const bf16x8*)(&ldsK[cur][(mt * 16 + l15) * 128 + (((kk * 4 + quad) ^ l15) << 3)]);
                #pragma unroll
                for (int mt = 0; mt < 4; ++mt)
                    accS[mt] = __builtin_amdgcn_mfma_f32_16x16x32_bf16(kf[mt], qf[kk], accS[mt], 0, 0, 0);
            }
            if (kt == qt) {
                const int ql = w * 16 + l15;
                #pragma unroll
                for (int mt = 0; mt < 4; ++mt)
                    #pragma unroll
                    for (int r = 0; r < 4; ++r)
                        if (mt * 16 + quad * 4 + r > ql) accS[mt][r] = -3.0e38f;
            }
            float mx = accS[0][0];
            #pragma unroll
            for (int mt = 0; mt < 4; ++mt)
                #pragma unroll
                for (int r = 0; r < 4; ++r) mx = fmaxf(mx, accS[mt][r]);
            mx = fmaxf(mx, __shfl_xor(mx, 16));
            mx = fmaxf(mx, __shfl_xor(mx, 32));
            const float mnew = fmaxf(mrun, mx);
            const float al = fast_exp2(mrun - mnew);
            float rs = 0.f;
            #pragma unroll
            for (int mt = 0; mt < 4; ++mt) {
                ushort4 pk;
                unsigned short* pe = (unsigned short*)&pk;
                #pragma unroll
                for (int r = 0; r < 4; ++r) {
                    const float p = fast_exp2(accS[mt][r] - mnew);
                    const unsigned short pb = f2bf(p);
                    pe[r] = pb;
                    rs += bf2f(pb);
                }
                *(ushort4*)(pw + l15 * 64 + (((mt * 4 + quad) ^ pswz) << 2)) = pk;
            }
            rs += __shfl_xor(rs, 16);
            rs += __shfl_xor(rs, 32);
            lrun = lrun * al + rs;
            mrun = mnew;
            float albr[4];
            #pragma unroll
            for (int r = 0; r < 4; ++r)
                albr[r] = __shfl(al, (lane & 48) | (quad << 2) | r);
            #pragma unroll
            for (int dt = 0; dt < 8; ++dt)
                #pragma unroll
                for (int r = 0; r < 4; ++r)
                    accO[dt][r] *= albr[r];
            asm volatile("s_waitcnt lgkmcnt(0)" ::: "memory");
            #pragma unroll
            for (int kk = 0; kk < 2; ++kk) {
                const bf16x8 pa = *(const bf16x8*)(pw + l15 * 64 + (((kk * 8 + quad * 2) ^ pswz) << 2));
                #pragma unroll
                for (int dt = 0; dt < 8; ++dt) {
                    const bf16x8 vf = *(const bf16x8*)(&ldsV[cur][(dt * 16 + l15) * 64 + (((kk * 4 + quad) ^ (l15 & 7)) << 3)]);
                    accO[dt] = __builtin_amdgcn_mfma_f32_16x16x32_bf16(pa, vf, accO[dt], 0, 0, 0);
                }
            }
            __syncthreads();
            cur ^= 1;
        }
        float linv[4];
        #pragma unroll
        for (int r = 0; r < 4; ++r)
            linv[r] = __shfl(lrun, (lane & 48) | (quad << 2) | r);
        #pragma unroll
        for (int r = 0; r < 4; ++r) {
            const float inv = 1.0f / linv[r];
            unsigned short* orow = AV + ((size_t)bb * kS + qrow0 + quad * 4 + r) * kDM + h * kDH;
            #pragma unroll
            for (int dt = 0; dt < 8; ++dt)
                orow[dt * 16 + l15] = f2bf(accO[dt][r] * inv);
        }
    }
}

extern "C" void kernel_launch(void* const* d_in, const int* in_sizes, int n_in,
                              void* d_out, int out_size, void* d_ws, size_t ws_size,
                              hipStream_t stream) {
    const float* X   = (const float*)d_in[0];
    const float* lng = (const float*)d_in[1];
    const float* lnb = (const float*)d_in[2];
    const float* Wq  = (const float*)d_in[3];
    const float* bq  = (const float*)d_in[4];
    const float* Wk  = (const float*)d_in[5];
    const float* bk  = (const float*)d_in[6];
    const float* Wv  = (const float*)d_in[7];
    const float* bv  = (const float*)d_in[8];
    const float* Wo  = (const float*)d_in[9];
    const float* bo  = (const float*)d_in[10];
    float* out = (float*)d_out;

    char* p = (char*)d_ws;
    unsigned short* Xn  = (unsigned short*)p; p += (size_t)kM * kDM * 2;
    unsigned short* Wqt = (unsigned short*)p; p += (size_t)kDM * kDM * 2;  // Wq|Wk|Wv contiguous
    unsigned short* Wkt = (unsigned short*)p; p += (size_t)kDM * kDM * 2;
    unsigned short* Wvt = (unsigned short*)p; p += (size_t)kDM * kDM * 2;
    unsigned short* Wot = (unsigned short*)p; p += (size_t)kDM * kDM * 2;
    unsigned short* Qb  = (unsigned short*)p; p += (size_t)kM * kDM * 2;
    unsigned short* Kb  = (unsigned short*)p; p += (size_t)kM * kDM * 2;
    unsigned short* Vtb = (unsigned short*)p; p += (size_t)kM * kDM * 2;
    unsigned short* AV  = (unsigned short*)p; p += (size_t)kM * kDM * 2;
    unsigned short* Vtmp = AV;        // alias: consumed by vtr before attn writes AV
    float* biasc = (float*)Vtb;       // alias: consumed by qkv-gemm before vtr writes Vtb

    const float qscale = 0.08838834764831845f * 1.4426950408889634f;

    ln_kernel<<<dim3(kM), dim3(256), 0, stream>>>(X, lng, lnb, Xn);
    wt_kernel<<<dim3(32, 32, 4), dim3(256), 0, stream>>>(Wq, Wk, Wv, Wo, Wqt, Wkt, Wvt, Wot);
    bias_pack<<<dim3(24), dim3(256), 0, stream>>>(bq, bk, bv, biasc);
    // fused QKV GEMM: 256x256 8-wave counted-vmcnt pipeline; N=6144 over [Wqt|Wkt|Wvt]
    gemm256_kernel<<<dim3(16, 24), dim3(512), 0, stream>>>(Xn, Wqt, biasc, Qb, Kb, Vtmp, qscale);
    vtr_kernel<<<dim3(32, 2, 32), dim3(256), 0, stream>>>(Vtmp, Vtb);
    attn_kernel<<<dim3(32, 16), dim3(256), 0, stream>>>(Qb, Kb, Vtb, AV);
    gemm_kernel<<<dim3(32, 16), dim3(256), 0, stream>>>(AV, Wot, bo, out, out, out, 1.0f, 1);
}

// Round 4
// 381.718 us; speedup vs baseline: 1.0353x; 1.0069x over previous
//
#include <hip/hip_runtime.h>
#include <cstdint>

constexpr int kDM = 2048;   // d_model
constexpr int kNH = 16;     // heads
constexpr int kDH = 128;    // head dim
constexpr int kS  = 2048;   // seq
constexpr int kM  = 4096;   // B*S rows

typedef __bf16 bf16x8 __attribute__((ext_vector_type(8)));
typedef float  f32x4  __attribute__((ext_vector_type(4)));

__device__ __forceinline__ unsigned short f2bf(float f) {
    union { float f; unsigned u; } v; v.f = f;
    unsigned u = v.u;
    u += 0x7fffu + ((u >> 16) & 1u);   // RNE
    return (unsigned short)(u >> 16);
}
__device__ __forceinline__ float bf2f(unsigned short b) {
    union { unsigned u; float f; } v; v.u = ((unsigned)b) << 16;
    return v.f;
}
__device__ __forceinline__ float fast_exp2(float x) {
#if __has_builtin(__builtin_amdgcn_exp2f)
    return __builtin_amdgcn_exp2f(x);
#else
    return exp2f(x);
#endif
}
// async global->LDS, 16B per lane, LDS dest = wave-uniform base + lane*16
__device__ __forceinline__ void load_lds16(const void* g, void* l) {
    auto gp = (__attribute__((address_space(1))) unsigned int*)(uintptr_t)g;
    auto lp = (__attribute__((address_space(3))) unsigned int*)(uintptr_t)l;
    __builtin_amdgcn_global_load_lds(gp, lp, 16, 0, 0);
}

// ---------------- LayerNorm: fp32 in -> bf16 out ----------------
__global__ __launch_bounds__(256) void ln_kernel(const float* __restrict__ X,
        const float* __restrict__ g, const float* __restrict__ b,
        unsigned short* __restrict__ Xn) {
    const int row = blockIdx.x;
    const float* xr = X + (size_t)row * kDM;
    const float4 v0 = ((const float4*)xr)[threadIdx.x];
    const float4 v1 = ((const float4*)xr)[threadIdx.x + 256];
    float s  = v0.x + v0.y + v0.z + v0.w + v1.x + v1.y + v1.z + v1.w;
    float sq = v0.x*v0.x + v0.y*v0.y + v0.z*v0.z + v0.w*v0.w
             + v1.x*v1.x + v1.y*v1.y + v1.z*v1.z + v1.w*v1.w;
    #pragma unroll
    for (int m = 1; m < 64; m <<= 1) { s += __shfl_xor(s, m); sq += __shfl_xor(sq, m); }
    __shared__ float ls[4], lq[4];
    if ((threadIdx.x & 63) == 0) { ls[threadIdx.x >> 6] = s; lq[threadIdx.x >> 6] = sq; }
    __syncthreads();
    s  = ls[0] + ls[1] + ls[2] + ls[3];
    sq = lq[0] + lq[1] + lq[2] + lq[3];
    const float mu   = s * (1.0f / kDM);
    const float rstd = rsqrtf(sq * (1.0f / kDM) - mu * mu + 1e-5f);
    unsigned short* xo = Xn + (size_t)row * kDM;
    {
        const float4 gg = ((const float4*)g)[threadIdx.x];
        const float4 bb = ((const float4*)b)[threadIdx.x];
        ushort4 o;
        o.x = f2bf((v0.x - mu) * rstd * gg.x + bb.x);
        o.y = f2bf((v0.y - mu) * rstd * gg.y + bb.y);
        o.z = f2bf((v0.z - mu) * rstd * gg.z + bb.z);
        o.w = f2bf((v0.w - mu) * rstd * gg.w + bb.w);
        ((ushort4*)xo)[threadIdx.x] = o;
    }
    {
        const float4 gg = ((const float4*)g)[threadIdx.x + 256];
        const float4 bb = ((const float4*)b)[threadIdx.x + 256];
        ushort4 o;
        o.x = f2bf((v1.x - mu) * rstd * gg.x + bb.x);
        o.y = f2bf((v1.y - mu) * rstd * gg.y + bb.y);
        o.z = f2bf((v1.z - mu) * rstd * gg.z + bb.z);
        o.w = f2bf((v1.w - mu) * rstd * gg.w + bb.w);
        ((ushort4*)xo)[threadIdx.x + 256] = o;
    }
}

// ------------- weight transpose+cast: W[K][N] f32 -> Wt[N][K] bf16 -------------
// 64x64 tiles; float4 global reads, odd-stride(65) LDS, 16B coalesced stores.
__global__ __launch_bounds__(256) void wt_kernel(
        const float* __restrict__ W0, const float* __restrict__ W1,
        const float* __restrict__ W2, const float* __restrict__ W3,
        unsigned short* __restrict__ T0, unsigned short* __restrict__ T1,
        unsigned short* __restrict__ T2, unsigned short* __restrict__ T3) {
    const float* W; unsigned short* T;
    switch (blockIdx.z) {
        case 0:  W = W0; T = T0; break;
        case 1:  W = W1; T = T1; break;
        case 2:  W = W2; T = T2; break;
        default: W = W3; T = T3; break;
    }
    __shared__ float tile[64][65];
    const int t = threadIdx.x;
    const int r0 = blockIdx.y * 64, c0 = blockIdx.x * 64;
    const int lr = t >> 4, lc = (t & 15) * 4;
    #pragma unroll
    for (int i = 0; i < 4; ++i) {
        const float4 v = *(const float4*)&W[(size_t)(r0 + lr + i * 16) * kDM + c0 + lc];
        float* tp = &tile[lr + i * 16][lc];
        tp[0] = v.x; tp[1] = v.y; tp[2] = v.z; tp[3] = v.w;
    }
    __syncthreads();
    const int g = t & 7;
    #pragma unroll
    for (int j = 0; j < 2; ++j) {
        const int orr = (t >> 3) + j * 32;
        union { unsigned short u[8]; uint4 v; } o;
        #pragma unroll
        for (int jj = 0; jj < 8; ++jj)
            o.u[jj] = f2bf(tile[g * 8 + jj][orr]);
        *(uint4*)&T[(size_t)(c0 + orr) * kDM + r0 + g * 8] = o.v;
    }
}

// --- bias concat: [bq|bk|bv] -> 6144 floats ---
__global__ __launch_bounds__(256) void bias_pack(const float* __restrict__ bq,
        const float* __restrict__ bk, const float* __restrict__ bv,
        float* __restrict__ o) {
    const int i = blockIdx.x * 256 + threadIdx.x;
    o[i] = (i < 2048) ? bq[i] : ((i < 4096) ? bk[i - 2048] : bv[i - 4096]);
}

// --- V transpose: [bh][s][dh] bf16 -> [bh][dh][s] bf16, 64x64 tiles ---
__global__ __launch_bounds__(256) void vtr_kernel(const unsigned short* __restrict__ Vin,
                                                  unsigned short* __restrict__ Vout) {
    __shared__ __align__(16) unsigned short tile[64 * 72];
    const int bhz = blockIdx.z;
    const int s0 = blockIdx.x * 64, d0 = blockIdx.y * 64;
    const int t = threadIdx.x;
    const unsigned short* src = Vin + ((size_t)bhz * kS + s0) * kDH + d0;
    #pragma unroll
    for (int i = 0; i < 2; ++i) {
        const int r = (t >> 3) + 32 * i;
        const int g = t & 7;
        *(uint4*)(tile + r * 72 + g * 8) = *(const uint4*)(src + (size_t)r * kDH + g * 8);
    }
    __syncthreads();
    unsigned short* dst = Vout + ((size_t)bhz * kDH + d0) * kS + s0;
    #pragma unroll
    for (int i = 0; i < 2; ++i) {
        const int d = (t >> 3) + 32 * i;
        const int sg = t & 7;
        union { unsigned short u[8]; uint4 v; } o;
        #pragma unroll
        for (int j = 0; j < 8; ++j)
            o.u[j] = tile[(sg * 8 + j) * 72 + d];
        *(uint4*)(dst + (size_t)d * kS + sg * 8) = o.v;
    }
}

// ------------- GEMM (legacy 128x128, m97 structure): out-proj only -------------
// R4: XCD swizzle REVERTED (R3 counters: FETCH +28MB, -4.3us on gemm256 --
// un-swizzled dispatch already shares B-panels temporally across XCDs).
__global__ __launch_bounds__(256) void gemm_kernel(
        const unsigned short* __restrict__ A, const unsigned short* __restrict__ Bt,
        const float* __restrict__ bias, void* __restrict__ C0, void* __restrict__ C1,
        void* __restrict__ C2, const float scale0, const int fp32out) {
    __shared__ __align__(16) unsigned short ldsA[2][128 * 32];
    __shared__ __align__(16) unsigned short ldsB[2][128 * 32];
    const int m0 = blockIdx.x * 128, n0 = blockIdx.y * 128;
    const int tid = threadIdx.x, lane = tid & 63, w = tid >> 6;
    const int wm = (w >> 1) * 64, wn = (w & 1) * 64;
    const int quad = lane >> 4, l15 = lane & 15;
    f32x4 acc[4][4] = {};
    const int srow = lane >> 2, scol = (lane & 3) * 8;
    for (int k0 = 0; k0 < kDM; k0 += 64) {
        __syncthreads();
        #pragma unroll
        for (int sub = 0; sub < 2; ++sub) {
            #pragma unroll
            for (int i = 0; i < 2; ++i) {
                const int c = w + i * 4;
                const int row = c * 16 + srow;
                const int kc = k0 + sub * 32 + scol;
                load_lds16(A  + (size_t)(m0 + row) * kDM + kc, &ldsA[sub][c * 512]);
                load_lds16(Bt + (size_t)(n0 + row) * kDM + kc, &ldsB[sub][c * 512]);
            }
        }
        __syncthreads();
        #pragma unroll
        for (int sub = 0; sub < 2; ++sub) {
            bf16x8 af[4], bfr[4];
            #pragma unroll
            for (int mt = 0; mt < 4; ++mt)
                af[mt] = *(const bf16x8*)(&ldsA[sub][(wm + mt * 16 + l15) * 32 + quad * 8]);
            #pragma unroll
            for (int nt = 0; nt < 4; ++nt)
                bfr[nt] = *(const bf16x8*)(&ldsB[sub][(wn + nt * 16 + l15) * 32 + quad * 8]);
            #pragma unroll
            for (int mt = 0; mt < 4; ++mt)
                #pragma unroll
                for (int nt = 0; nt < 4; ++nt)
                    acc[mt][nt] = __builtin_amdgcn_mfma_f32_16x16x32_bf16(af[mt], bfr[nt], acc[mt][nt], 0, 0, 0);
        }
    }
    const int proj = n0 >> 11;
    void* Cb = (proj == 0) ? C0 : ((proj == 1) ? C1 : C2);
    const float scl = (proj == 0) ? scale0 : 1.0f;
    #pragma unroll
    for (int mt = 0; mt < 4; ++mt) {
        #pragma unroll
        for (int nt = 0; nt < 4; ++nt) {
            const int ng = n0 + wn + nt * 16 + l15;
            const float bv = bias[ng];
            const int col = ng & 2047;
            const int h = col >> 7, dh = col & 127;
            #pragma unroll
            for (int r = 0; r < 4; ++r) {
                const int mg = m0 + wm + mt * 16 + quad * 4 + r;
                const float val = (acc[mt][nt][r] + bv) * scl;
                if (fp32out) {
                    ((float*)Cb)[(size_t)mg * kDM + ng] = val;
                } else {
                    const int bb = mg >> 11, ss = mg & 2047;
                    ((unsigned short*)Cb)[((size_t)(bb * kNH + h) * kS + ss) * kDH + dh] = f2bf(val);
                }
            }
        }
    }
}

// ------------- GEMM 256x256, 8-wave, BK=64, 4-phase counted-vmcnt pipeline -----
// R4: XCD swizzle reverted (see gemm_kernel note). R2-proven config: 846 TF,
// 0 bank conflicts, FETCH 115MB.
__global__ __launch_bounds__(512, 2) void gemm256_kernel(
        const unsigned short* __restrict__ A, const unsigned short* __restrict__ Bt,
        const float* __restrict__ bias, void* __restrict__ C0, void* __restrict__ C1,
        void* __restrict__ C2, const float scale0) {
    __shared__ __align__(16) unsigned short sA[2][2 * 128 * 64];
    __shared__ __align__(16) unsigned short sB[2][2 * 128 * 64];
    const int tid = threadIdx.x, lane = tid & 63, w = tid >> 6;
    const int quad = lane >> 4, l15 = lane & 15;
    const int wr = w >> 2, wc = w & 3;          // 2M x 4N wave grid
    const int m0 = blockIdx.x * 256, n0 = blockIdx.y * 256;
    const int srow = lane >> 3;
    const int scol = ((lane & 7) ^ srow) * 8;   // inverse-swizzled global source
    size_t aOff[2], bOff[2]; int lOff[2];
    #pragma unroll
    for (int i = 0; i < 2; ++i) {
        const int wrow = (i * 8 + w) * 8 + srow;     // row within a 128-row half
        aOff[i] = (size_t)(m0 + wrow) * kDM + scol;  // + h*128*kDM + kt*64
        bOff[i] = (size_t)(n0 + wrow) * kDM + scol;
        lOff[i] = (i * 8 + w) * 512;                 // + h*8192 (elements)
    }
    const int swz = l15 & 7;
    int colq[2];
    #pragma unroll
    for (int ks = 0; ks < 2; ++ks) colq[ks] = ((ks * 4 + quad) ^ swz) * 8;

#define STG_A(buf, h, kt) { \
    load_lds16(A  + aOff[0] + (size_t)(h) * (128 * kDM) + (kt) * 64, &sA[buf][(h) * 8192 + lOff[0]]); \
    load_lds16(A  + aOff[1] + (size_t)(h) * (128 * kDM) + (kt) * 64, &sA[buf][(h) * 8192 + lOff[1]]); }
#define STG_B(buf, h, kt) { \
    load_lds16(Bt + bOff[0] + (size_t)(h) * (128 * kDM) + (kt) * 64, &sB[buf][(h) * 8192 + lOff[0]]); \
    load_lds16(Bt + bOff[1] + (size_t)(h) * (128 * kDM) + (kt) * 64, &sB[buf][(h) * 8192 + lOff[1]]); }

    f32x4 acc[8][4] = {};
    STG_A(0, 0, 0); STG_A(0, 1, 0);
    STG_B(0, 0, 0); STG_B(0, 1, 0);
    STG_B(1, 0, 1); STG_A(1, 0, 1);
    asm volatile("s_waitcnt vmcnt(4)" ::: "memory");
    __builtin_amdgcn_s_barrier();

    const int NT = kDM / 64;                    // 32 K-tiles
    bf16x8 af[4][2], bl[2][2], bh[2][2];
    for (int t = 0; t < NT; ++t) {
        const int cur = t & 1, nxt = cur ^ 1;
        // ---- phase 1: A-lo + B-lo reads; stage B1^{t+1}; mfma (m-lo x n-lo)
        #pragma unroll
        for (int mt = 0; mt < 4; ++mt)
            #pragma unroll
            for (int ks = 0; ks < 2; ++ks)
                af[mt][ks] = *(const bf16x8*)(&sA[cur][(wr * 128 + mt * 16 + l15) * 64 + colq[ks]]);
        #pragma unroll
        for (int nt = 0; nt < 2; ++nt)
            #pragma unroll
            for (int ks = 0; ks < 2; ++ks)
                bl[nt][ks] = *(const bf16x8*)(&sB[cur][(wc * 64 + nt * 16 + l15) * 64 + colq[ks]]);
        if (t + 1 < NT) STG_B(nxt, 1, t + 1);
        __builtin_amdgcn_s_barrier();
        asm volatile("s_waitcnt lgkmcnt(0)" ::: "memory");
        __builtin_amdgcn_s_setprio(1);
        #pragma unroll
        for (int mt = 0; mt < 4; ++mt)
            #pragma unroll
            for (int nt = 0; nt < 2; ++nt)
                #pragma unroll
                for (int ks = 0; ks < 2; ++ks)
                    acc[mt][nt] = __builtin_amdgcn_mfma_f32_16x16x32_bf16(af[mt][ks], bl[nt][ks], acc[mt][nt], 0, 0, 0);
        __builtin_amdgcn_s_setprio(0);
        __builtin_amdgcn_s_barrier();
        // ---- phase 2: B-hi reads; stage A1^{t+1}; mfma (m-lo x n-hi)
        #pragma unroll
        for (int nt = 0; nt < 2; ++nt)
            #pragma unroll
            for (int ks = 0; ks < 2; ++ks)
                bh[nt][ks] = *(const bf16x8*)(&sB[cur][(wc * 64 + 32 + nt * 16 + l15) * 64 + colq[ks]]);
        if (t + 1 < NT) STG_A(nxt, 1, t + 1);
        __builtin_amdgcn_s_barrier();
        asm volatile("s_waitcnt lgkmcnt(0)" ::: "memory");
        __builtin_amdgcn_s_setprio(1);
        #pragma unroll
        for (int mt = 0; mt < 4; ++mt)
            #pragma unroll
            for (int nt = 0; nt < 2; ++nt)
                #pragma unroll
                for (int ks = 0; ks < 2; ++ks)
                    acc[mt][2 + nt] = __builtin_amdgcn_mfma_f32_16x16x32_bf16(af[mt][ks], bh[nt][ks], acc[mt][2 + nt], 0, 0, 0);
        __builtin_amdgcn_s_setprio(0);
        __builtin_amdgcn_s_barrier();
        // ---- phase 3: A-hi reads (reuse af regs); stage B0^{t+2}; mfma (m-hi x n-hi)
        #pragma unroll
        for (int mt = 0; mt < 4; ++mt)
            #pragma unroll
            for (int ks = 0; ks < 2; ++ks)
                af[mt][ks] = *(const bf16x8*)(&sA[cur][(wr * 128 + 64 + mt * 16 + l15) * 64 + colq[ks]]);
        if (t + 2 < NT) STG_B(cur, 0, t + 2);
        __builtin_amdgcn_s_barrier();
        asm volatile("s_waitcnt lgkmcnt(0)" ::: "memory");
        __builtin_amdgcn_s_setprio(1);
        #pragma unroll
        for (int mt = 0; mt < 4; ++mt)
            #pragma unroll
            for (int nt = 0; nt < 2; ++nt)
                #pragma unroll
                for (int ks = 0; ks < 2; ++ks)
                    acc[4 + mt][2 + nt] = __builtin_amdgcn_mfma_f32_16x16x32_bf16(af[mt][ks], bh[nt][ks], acc[4 + mt][2 + nt], 0, 0, 0);
        __builtin_amdgcn_s_setprio(0);
        __builtin_amdgcn_s_barrier();
        // ---- phase 4: regs only; stage A0^{t+2}; mfma (m-hi x n-lo); boundary
        if (t + 2 < NT) STG_A(cur, 0, t + 2);
        __builtin_amdgcn_s_barrier();
        __builtin_amdgcn_s_setprio(1);
        #pragma unroll
        for (int mt = 0; mt < 4; ++mt)
            #pragma unroll
            for (int nt = 0; nt < 2; ++nt)
                #pragma unroll
                for (int ks = 0; ks < 2; ++ks)
                    acc[4 + mt][nt] = __builtin_amdgcn_mfma_f32_16x16x32_bf16(af[mt][ks], bl[nt][ks], acc[4 + mt][nt], 0, 0, 0);
        __builtin_amdgcn_s_setprio(0);
        if (t + 1 < NT) {
            if (t + 2 < NT) { asm volatile("s_waitcnt vmcnt(4)" ::: "memory"); }
            else            { asm volatile("s_waitcnt vmcnt(0)" ::: "memory"); }
            __builtin_amdgcn_s_barrier();
        }
    }
#undef STG_A
#undef STG_B
    const int proj = n0 >> 11;
    void* Cb = (proj == 0) ? C0 : ((proj == 1) ? C1 : C2);
    const float scl = (proj == 0) ? scale0 : 1.0f;
    #pragma unroll
    for (int mt = 0; mt < 8; ++mt) {
        #pragma unroll
        for (int nt = 0; nt < 4; ++nt) {
            const int ng = n0 + wc * 64 + nt * 16 + l15;
            const float bv = bias[ng];
            const int col = ng & 2047;
            const int h = col >> 7, dh = col & 127;
            #pragma unroll
            for (int r = 0; r < 4; ++r) {
                const int mg = m0 + wr * 128 + mt * 16 + quad * 4 + r;
                const float val = (acc[mt][nt][r] + bv) * scl;
                const int bb = mg >> 11, ss = mg & 2047;
                ((unsigned short*)Cb)[((size_t)(bb * kNH + h) * kS + ss) * kDH + dh] = f2bf(val);
            }
        }
    }
}

// ------------- causal flash attention, S^T form, paired q-tiles -------------
// R4: + T13 defer-max (skip O/l rescale when __all(mx - mrun <= 8): exact up to
// bf16 rounding since num & denom scale identically; triggers ~every tile after
// tile 0 on bounded scores) and T5 setprio around both MFMA clusters.
__global__ __launch_bounds__(256, 2) void attn_kernel(
        const unsigned short* __restrict__ Q, const unsigned short* __restrict__ Kk,
        const unsigned short* __restrict__ Vt, unsigned short* __restrict__ AV) {
    __shared__ __align__(16) unsigned short ldsK[2][64 * 128];   // swizzled [key][d]
    __shared__ __align__(16) unsigned short ldsV[2][128 * 64];   // swizzled [d][key]
    __shared__ __align__(16) unsigned short ldsP[4 * 16 * 64];   // per-wave swizzled [q][key]
    const int bh = blockIdx.x, pr = blockIdx.y;
    const unsigned short* Qb = Q  + (size_t)bh * kS * kDH;
    const unsigned short* Kb = Kk + (size_t)bh * kS * kDH;
    const unsigned short* Vb = Vt + (size_t)bh * kDH * kS;
    const int tid = threadIdx.x, lane = tid & 63, w = tid >> 6;
    const int quad = lane >> 4, l15 = lane & 15;
    int kSrc[4], vSrc[4], ldst[4];
    #pragma unroll
    for (int i = 0; i < 4; ++i) {
        const int c = w * 4 + i;
        const int rK = c * 4 + (lane >> 4);
        const int gK = (lane & 15) ^ (rK & 15);
        kSrc[i] = rK * kDH + gK * 8;
        const int dV = c * 8 + (lane >> 3);
        const int gV = (lane & 7) ^ (dV & 7);
        vSrc[i] = dV * kS + gV * 8;
        ldst[i] = c * 512;
    }
    unsigned short* pw = ldsP + w * 1024;
    const int pswz = 2 * (l15 & 7);
    const int bb = bh >> 4, h = bh & 15;
    for (int half = 0; half < 2; ++half) {
        const int qt = half ? (31 - pr) : pr;
        const int qrow0 = qt * 64 + w * 16;
        bf16x8 qf[4];
        #pragma unroll
        for (int kk = 0; kk < 4; ++kk)
            qf[kk] = *(const bf16x8*)(Qb + (size_t)(qrow0 + l15) * kDH + kk * 32 + quad * 8);
        f32x4 accO[8] = {};
        float mrun = -3.0e38f, lrun = 0.0f;
        #pragma unroll
        for (int i = 0; i < 4; ++i) {
            load_lds16(Kb + kSrc[i], &ldsK[0][ldst[i]]);
            load_lds16(Vb + vSrc[i], &ldsV[0][ldst[i]]);
        }
        __syncthreads();
        int cur = 0;
        for (int kt = 0; kt <= qt; ++kt) {
            if (kt < qt) {
                #pragma unroll
                for (int i = 0; i < 4; ++i) {
                    load_lds16(Kb + (size_t)(kt + 1) * (64 * kDH) + kSrc[i], &ldsK[cur ^ 1][ldst[i]]);
                    load_lds16(Vb + (kt + 1) * 64 + vSrc[i], &ldsV[cur ^ 1][ldst[i]]);
                }
            }
            f32x4 accS[4] = {};
            __builtin_amdgcn_s_setprio(1);
            #pragma unroll
            for (int kk = 0; kk < 4; ++kk) {
                bf16x8 kf[4];
                #pragma unroll
                for (int mt = 0; mt < 4; ++mt)
                    kf[mt] = *(const bf16x8*)(&ldsK[cur][(mt * 16 + l15) * 128 + (((kk * 4 + quad) ^ l15) << 3)]);
                #pragma unroll
                for (int mt = 0; mt < 4; ++mt)
                    accS[mt] = __builtin_amdgcn_mfma_f32_16x16x32_bf16(kf[mt], qf[kk], accS[mt], 0, 0, 0);
            }
            __builtin_amdgcn_s_setprio(0);
            if (kt == qt) {
                const int ql = w * 16 + l15;
                #pragma unroll
                for (int mt = 0; mt < 4; ++mt)
                    #pragma unroll
                    for (int r = 0; r < 4; ++r)
                        if (mt * 16 + quad * 4 + r > ql) accS[mt][r] = -3.0e38f;
            }
            float mx = accS[0][0];
            #pragma unroll
            for (int mt = 0; mt < 4; ++mt)
                #pragma unroll
                for (int r = 0; r < 4; ++r) mx = fmaxf(mx, accS[mt][r]);
            mx = fmaxf(mx, __shfl_xor(mx, 16));
            mx = fmaxf(mx, __shfl_xor(mx, 32));
            // T13 defer-max: rescale only when the new tile max exceeds mrun+8.
            // (mx, mrun uniform across quads; __all -> wave-uniform branch)
            if (!__all(mx - mrun <= 8.0f)) {
                const float mnew = fmaxf(mrun, mx);
                const float al = fast_exp2(mrun - mnew);
                lrun *= al;
                float albr[4];
                #pragma unroll
                for (int r = 0; r < 4; ++r)
                    albr[r] = __shfl(al, (lane & 48) | (quad << 2) | r);
                #pragma unroll
                for (int dt = 0; dt < 8; ++dt)
                    #pragma unroll
                    for (int r = 0; r < 4; ++r)
                        accO[dt][r] *= albr[r];
                mrun = mnew;
            }
            float rs = 0.f;
            #pragma unroll
            for (int mt = 0; mt < 4; ++mt) {
                ushort4 pk;
                unsigned short* pe = (unsigned short*)&pk;
                #pragma unroll
                for (int r = 0; r < 4; ++r) {
                    const float p = fast_exp2(accS[mt][r] - mrun);
                    const unsigned short pb = f2bf(p);
                    pe[r] = pb;
                    rs += bf2f(pb);
                }
                *(ushort4*)(pw + l15 * 64 + (((mt * 4 + quad) ^ pswz) << 2)) = pk;
            }
            rs += __shfl_xor(rs, 16);
            rs += __shfl_xor(rs, 32);
            lrun += rs;
            asm volatile("s_waitcnt lgkmcnt(0)" ::: "memory");  // P writes visible to own wave
            __builtin_amdgcn_s_setprio(1);
            #pragma unroll
            for (int kk = 0; kk < 2; ++kk) {
                const bf16x8 pa = *(const bf16x8*)(pw + l15 * 64 + (((kk * 8 + quad * 2) ^ pswz) << 2));
                #pragma unroll
                for (int dt = 0; dt < 8; ++dt) {
                    const bf16x8 vf = *(const bf16x8*)(&ldsV[cur][(dt * 16 + l15) * 64 + (((kk * 4 + quad) ^ (l15 & 7)) << 3)]);
                    accO[dt] = __builtin_amdgcn_mfma_f32_16x16x32_bf16(pa, vf, accO[dt], 0, 0, 0);
                }
            }
            __builtin_amdgcn_s_setprio(0);
            __syncthreads();
            cur ^= 1;
        }
        float linv[4];
        #pragma unroll
        for (int r = 0; r < 4; ++r)
            linv[r] = __shfl(lrun, (lane & 48) | (quad << 2) | r);
        #pragma unroll
        for (int r = 0; r < 4; ++r) {
            const float inv = 1.0f / linv[r];
            unsigned short* orow = AV + ((size_t)bb * kS + qrow0 + quad * 4 + r) * kDM + h * kDH;
            #pragma unroll
            for (int dt = 0; dt < 8; ++dt)
                orow[dt * 16 + l15] = f2bf(accO[dt][r] * inv);
        }
    }
}

extern "C" void kernel_launch(void* const* d_in, const int* in_sizes, int n_in,
                              void* d_out, int out_size, void* d_ws, size_t ws_size,
                              hipStream_t stream) {
    const float* X   = (const float*)d_in[0];
    const float* lng = (const float*)d_in[1];
    const float* lnb = (const float*)d_in[2];
    const float* Wq  = (const float*)d_in[3];
    const float* bq  = (const float*)d_in[4];
    const float* Wk  = (const float*)d_in[5];
    const float* bk  = (const float*)d_in[6];
    const float* Wv  = (const float*)d_in[7];
    const float* bv  = (const float*)d_in[8];
    const float* Wo  = (const float*)d_in[9];
    const float* bo  = (const float*)d_in[10];
    float* out = (float*)d_out;

    char* p = (char*)d_ws;
    unsigned short* Xn  = (unsigned short*)p; p += (size_t)kM * kDM * 2;
    unsigned short* Wqt = (unsigned short*)p; p += (size_t)kDM * kDM * 2;  // Wq|Wk|Wv contiguous
    unsigned short* Wkt = (unsigned short*)p; p += (size_t)kDM * kDM * 2;
    unsigned short* Wvt = (unsigned short*)p; p += (size_t)kDM * kDM * 2;
    unsigned short* Wot = (unsigned short*)p; p += (size_t)kDM * kDM * 2;
    unsigned short* Qb  = (unsigned short*)p; p += (size_t)kM * kDM * 2;
    unsigned short* Kb  = (unsigned short*)p; p += (size_t)kM * kDM * 2;
    unsigned short* Vtb = (unsigned short*)p; p += (size_t)kM * kDM * 2;
    unsigned short* AV  = (unsigned short*)p; p += (size_t)kM * kDM * 2;
    unsigned short* Vtmp = AV;        // alias: consumed by vtr before attn writes AV
    float* biasc = (float*)Vtb;       // alias: consumed by qkv-gemm before vtr writes Vtb

    const float qscale = 0.08838834764831845f * 1.4426950408889634f;

    ln_kernel<<<dim3(kM), dim3(256), 0, stream>>>(X, lng, lnb, Xn);
    wt_kernel<<<dim3(32, 32, 4), dim3(256), 0, stream>>>(Wq, Wk, Wv, Wo, Wqt, Wkt, Wvt, Wot);
    bias_pack<<<dim3(24), dim3(256), 0, stream>>>(bq, bk, bv, biasc);
    // fused QKV GEMM: 256x256 8-wave counted-vmcnt pipeline; N=6144 over [Wqt|Wkt|Wvt]
    gemm256_kernel<<<dim3(16, 24), dim3(512), 0, stream>>>(Xn, Wqt, biasc, Qb, Kb, Vtmp, qscale);
    vtr_kernel<<<dim3(32, 2, 32), dim3(256), 0, stream>>>(Vtmp, Vtb);
    attn_kernel<<<dim3(32, 16), dim3(256), 0, stream>>>(Qb, Kb, Vtb, AV);
    gemm_kernel<<<dim3(32, 16), dim3(256), 0, stream>>>(AV, Wot, bo, out, out, out, 1.0f, 1);
}